// Round 4
// baseline (541.035 us; speedup 1.0000x reference)
//
#include <hip/hip_runtime.h>

#define EPSV 1e-5f

typedef __attribute__((ext_vector_type(8))) short short8;
typedef __attribute__((ext_vector_type(4))) float f32x4;

// ---------------- init: cnt=0 ----------------
__global__ __launch_bounds__(256) void init_k(int* __restrict__ cnt, int nnodes) {
    int i = blockIdx.x * 256 + threadIdx.x;
    if (i < nnodes) cnt[i] = 0;
}

// ---------------- graph segment starts via binary search on sorted batch ----
__global__ __launch_bounds__(128) void gstart_k(const int* __restrict__ batch,
                                                int* __restrict__ gstart,
                                                int nnodes, int ngraphs) {
    int g = threadIdx.x;
    if (g > ngraphs) return;
    int lo = 0, hi = nnodes;
    while (lo < hi) {
        int mid = (lo + hi) >> 1;
        if (batch[mid] < g) lo = mid + 1; else hi = mid;
    }
    gstart[g] = lo;
}

__global__ __launch_bounds__(256) void degcount_k(const int* __restrict__ dst,
                                                  int* __restrict__ cnt,
                                                  int nedges) {
    int i = blockIdx.x * 256 + threadIdx.x;
    if (i < nedges) atomicAdd(&cnt[dst[i]], 1);
}

__global__ __launch_bounds__(256) void dinv_k(const int* __restrict__ cnt,
                                              float* __restrict__ dinv, int nnodes) {
    int i = blockIdx.x * 256 + threadIdx.x;
    if (i < nnodes) dinv[i] = rsqrtf(1.0f + (float)cnt[i]);
}

// ---------------- exclusive scan of cnt[] -> rowptr[] ------------------------
__global__ __launch_bounds__(256) void scan1_k(const int* __restrict__ cnt,
                                               int* __restrict__ rowptr,
                                               int* __restrict__ bsum, int n) {
    __shared__ int sh[256];
    const int tx = threadIdx.x;
    const int base = blockIdx.x * 1024;
    int v[4];
    int s = 0;
#pragma unroll
    for (int j = 0; j < 4; j++) {
        int idx = base + tx * 4 + j;
        v[j] = (idx < n) ? cnt[idx] : 0;
        s += v[j];
    }
    sh[tx] = s;
    __syncthreads();
#pragma unroll
    for (int off = 1; off < 256; off <<= 1) {
        int t = (tx >= off) ? sh[tx - off] : 0;
        __syncthreads();
        sh[tx] += t;
        __syncthreads();
    }
    int run = sh[tx] - s;
#pragma unroll
    for (int j = 0; j < 4; j++) {
        int idx = base + tx * 4 + j;
        if (idx < n) rowptr[idx] = run;
        run += v[j];
    }
    if (tx == 255) bsum[blockIdx.x] = sh[255];
}

__global__ __launch_bounds__(64) void scan2_k(int* __restrict__ bsum, int nb) {
    __shared__ int sh[64];
    const int tx = threadIdx.x;
    int v = (tx < nb) ? bsum[tx] : 0;
    sh[tx] = v;
    __syncthreads();
#pragma unroll
    for (int off = 1; off < 64; off <<= 1) {
        int t = (tx >= off) ? sh[tx - off] : 0;
        __syncthreads();
        sh[tx] += t;
        __syncthreads();
    }
    if (tx < nb) bsum[tx] = sh[tx] - v;
}

__global__ __launch_bounds__(256) void scan3_k(int* __restrict__ rowptr,
                                               int* __restrict__ cur,
                                               const int* __restrict__ bsum,
                                               int n, int nedges) {
    const int tx = threadIdx.x;
    const int base = blockIdx.x * 1024;
    int off = bsum[blockIdx.x];
#pragma unroll
    for (int j = 0; j < 4; j++) {
        int idx = base + tx * 4 + j;
        if (idx < n) {
            int r = rowptr[idx] + off;
            rowptr[idx] = r;
            cur[idx] = r;
        }
    }
    if (blockIdx.x == 0 && tx == 0) rowptr[n] = nedges;
}

__global__ __launch_bounds__(256) void fill_k(const int* __restrict__ src,
                                              const int* __restrict__ dst,
                                              int* __restrict__ cur,
                                              int* __restrict__ esrc, int nedges) {
    int i = blockIdx.x * 256 + threadIdx.x;
    if (i >= nedges) return;
    int pos = atomicAdd(&cur[dst[i]], 1);
    esrc[pos] = src[i];
}

// ---------------- W prep: transpose + bf16 hi/lo split -----------------------
// wThi/wTlo[c][k] (ushort bf16 bits), c in [0,128), k in [0,K)
template <int K>
__global__ __launch_bounds__(256) void wprep_k(const float* __restrict__ W,
                                               unsigned short* __restrict__ wThi,
                                               unsigned short* __restrict__ wTlo) {
    int i = blockIdx.x * 256 + threadIdx.x;
    if (i >= K * 128) return;
    int k = i >> 7, c = i & 127;
    float x = W[i];
    unsigned u = __builtin_bit_cast(unsigned, x);
    unsigned short hi = (unsigned short)(u >> 16);
    float hif = __builtin_bit_cast(float, u & 0xffff0000u);
    float lof = x - hif;
    unsigned short lo = (unsigned short)(__builtin_bit_cast(unsigned, lof) >> 16);
    wThi[c * K + k] = hi;
    wTlo[c * K + k] = lo;
}

// ---------------- MFMA GEMM: H[nrows][128] = X[nrows][K] @ W[K][128] ---------
// Split-bf16: X = xh + xl, W = wh + wl; acc += xh*wh + xl*wh + xh*wl (fp32 acc).
// Block = 256 thr = 4 waves; wave owns a 16-row x 128-col stripe. No LDS.
template <int K>
__global__ __launch_bounds__(256) void gemm_mfma_k(const float* __restrict__ X,
                                                   const unsigned short* __restrict__ wThi,
                                                   const unsigned short* __restrict__ wTlo,
                                                   float* __restrict__ H, int nrows) {
    const int tx = threadIdx.x;
    const int wave = tx >> 6;
    const int l = tx & 63;
    const int lrow = l & 15;   // A-row in stripe / C-col in group
    const int kgrp = l >> 4;   // 0..3: k-subblock of 8
    const int row0 = blockIdx.x * 64 + wave * 16;

    int arow = row0 + lrow;
    if (arow >= nrows) arow = nrows - 1;   // clamp (duplicate load, store guarded)
    const float* xrow = X + (size_t)arow * K + kgrp * 8;

    f32x4 acc[8];
#pragma unroll
    for (int g = 0; g < 8; g++) acc[g] = (f32x4){0.f, 0.f, 0.f, 0.f};

#pragma unroll 2
    for (int k0 = 0; k0 < K; k0 += 32) {
        // A fragment: 8 contiguous f32 -> bf16 hi/lo (truncate; lo catches rest)
        f32x4 x0 = *reinterpret_cast<const f32x4*>(xrow + k0);
        f32x4 x1 = *reinterpret_cast<const f32x4*>(xrow + k0 + 4);
        short8 ah, al;
#pragma unroll
        for (int j = 0; j < 8; j++) {
            float f = (j < 4) ? x0[j] : x1[j - 4];
            unsigned u = __builtin_bit_cast(unsigned, f);
            ah[j] = (short)(u >> 16);
            float hif = __builtin_bit_cast(float, u & 0xffff0000u);
            float lof = f - hif;
            al[j] = (short)(__builtin_bit_cast(unsigned, lof) >> 16);
        }
#pragma unroll
        for (int g = 0; g < 8; g++) {
            const size_t boff = (size_t)(g * 16 + lrow) * K + k0 + kgrp * 8;
            short8 bh = *reinterpret_cast<const short8*>(wThi + boff);
            short8 bl = *reinterpret_cast<const short8*>(wTlo + boff);
            acc[g] = __builtin_amdgcn_mfma_f32_16x16x32_bf16(ah, bh, acc[g], 0, 0, 0);
            acc[g] = __builtin_amdgcn_mfma_f32_16x16x32_bf16(al, bh, acc[g], 0, 0, 0);
            acc[g] = __builtin_amdgcn_mfma_f32_16x16x32_bf16(ah, bl, acc[g], 0, 0, 0);
        }
    }

    // C: row = row0 + kgrp*4 + r, col = g*16 + lrow  (verified m89 mapping)
#pragma unroll
    for (int r = 0; r < 4; r++) {
        int row = row0 + kgrp * 4 + r;
        if (row < nrows) {
            float* hrow = H + (size_t)row * 128 + lrow;
#pragma unroll
            for (int g = 0; g < 8; g++) hrow[g * 16] = acc[g][r];
        }
    }
}

// ---------------- fused aggregate: CSR gather + selfloop + bias + BN + ReLU --
__global__ __launch_bounds__(256) void agg_k(const float* __restrict__ H,
                                             const int* __restrict__ rowptr,
                                             const int* __restrict__ esrc,
                                             const float* __restrict__ dinv,
                                             const float* __restrict__ bias,
                                             const float* __restrict__ gamma,
                                             const float* __restrict__ beta,
                                             const float* __restrict__ rm,
                                             const float* __restrict__ rv,
                                             float* __restrict__ OUT,
                                             int nnodes) {
    const int node = blockIdx.x * 4 + (threadIdx.x >> 6);
    if (node >= nnodes) return;
    const int l = threadIdx.x & 63;
    const int c = l * 2;
    const float dn = dinv[node];

    float2 hv = *reinterpret_cast<const float2*>(H + (size_t)node * 128 + c);
    float2 acc = make_float2(hv.x * dn * dn, hv.y * dn * dn);
    float2 acc2 = make_float2(0.f, 0.f);

    const int beg = rowptr[node], end = rowptr[node + 1];
    int j = beg;
    for (; j + 1 < end; j += 2) {
        int s0 = esrc[j], s1 = esrc[j + 1];
        float n0 = dinv[s0] * dn, n1 = dinv[s1] * dn;
        float2 h0 = *reinterpret_cast<const float2*>(H + (size_t)s0 * 128 + c);
        float2 h1 = *reinterpret_cast<const float2*>(H + (size_t)s1 * 128 + c);
        acc.x += h0.x * n0;  acc.y += h0.y * n0;
        acc2.x += h1.x * n1; acc2.y += h1.y * n1;
    }
    if (j < end) {
        int s0 = esrc[j];
        float n0 = dinv[s0] * dn;
        float2 h0 = *reinterpret_cast<const float2*>(H + (size_t)s0 * 128 + c);
        acc.x += h0.x * n0; acc.y += h0.y * n0;
    }
    acc.x += acc2.x; acc.y += acc2.y;

    float v0 = acc.x + bias[c];
    float v1 = acc.y + bias[c + 1];
    v0 = (v0 - rm[c])     * rsqrtf(rv[c] + EPSV)     * gamma[c]     + beta[c];
    v1 = (v1 - rm[c + 1]) * rsqrtf(rv[c + 1] + EPSV) * gamma[c + 1] + beta[c + 1];
    v0 = fmaxf(v0, 0.0f);
    v1 = fmaxf(v1, 0.0f);

    *reinterpret_cast<float2*>(OUT + (size_t)node * 128 + c) = make_float2(v0, v1);
}

// ---------------- mean pool over contiguous graph segments ------------------
__global__ __launch_bounds__(256) void pool_k(const float* __restrict__ V,
                                              const int* __restrict__ gstart,
                                              float* __restrict__ pooled) {
    __shared__ float sh[256];
    const int g = blockIdx.x;
    const int tx = threadIdx.x;
    const int ch = tx & 127;
    const int sub = tx >> 7;
    const int beg = gstart[g], end = gstart[g + 1];
    float acc = 0.0f;
    for (int i = beg + sub; i < end; i += 2)
        acc += V[(size_t)i * 128 + ch];
    sh[tx] = acc;
    __syncthreads();
    if (tx < 128) {
        float tot = sh[tx] + sh[tx + 128];
        float cnt = fmaxf((float)(end - beg), 1.0f);
        pooled[g * 128 + tx] = tot / cnt;
    }
}

// ---------------- final: out[g][o] = pooled[g] @ Wl + bl ---------------------
__global__ __launch_bounds__(128) void final_k(const float* __restrict__ pooled,
                                               const float* __restrict__ Wl,
                                               const float* __restrict__ bl,
                                               float* __restrict__ out) {
    int tx = threadIdx.x;
    int g = tx >> 1, o = tx & 1;
    float s = 0.0f;
#pragma unroll 8
    for (int c = 0; c < 128; c++) s += pooled[g * 128 + c] * Wl[c * 2 + o];
    out[tx] = s + bl[o];
}

extern "C" void kernel_launch(void* const* d_in, const int* in_sizes, int n_in,
                              void* d_out, int out_size, void* d_ws, size_t ws_size,
                              hipStream_t stream) {
    const float* x      = (const float*)d_in[0];
    const int*   ei     = (const int*)d_in[1];
    const int*   batch  = (const int*)d_in[2];
    const float* W1     = (const float*)d_in[3];
    const float* b1     = (const float*)d_in[4];
    const float* gamma1 = (const float*)d_in[5];
    const float* beta1  = (const float*)d_in[6];
    const float* rm1    = (const float*)d_in[7];
    const float* rv1    = (const float*)d_in[8];
    const float* W2     = (const float*)d_in[9];
    const float* b2     = (const float*)d_in[10];
    const float* gamma2 = (const float*)d_in[11];
    const float* beta2  = (const float*)d_in[12];
    const float* rm2    = (const float*)d_in[13];
    const float* rv2    = (const float*)d_in[14];
    const float* Wl     = (const float*)d_in[15];
    const float* bl     = (const float*)d_in[16];
    float* out = (float*)d_out;

    const int nnodes  = in_sizes[2];
    const int nedges  = in_sizes[1] / 2;
    const int ngraphs = 64;
    const int* srcp = ei;
    const int* dstp = ei + nedges;

    float* wsA    = (float*)d_ws;                       // [nnodes*128]
    float* wsB    = wsA + (size_t)nnodes * 128;         // [nnodes*128]
    float* dinv   = wsB + (size_t)nnodes * 128;         // [nnodes]
    float* pooled = dinv + nnodes;                      // [64*128]
    int*   cnt    = (int*)(pooled + 64 * 128);          // [nnodes]
    int*   rowptr = cnt + nnodes;                       // [nnodes+1]
    int*   cur    = rowptr + nnodes + 1;                // [nnodes]
    int*   bsum   = cur + nnodes;                       // [64]
    int*   gstart = bsum + 64;                          // [65]
    int*   esrc   = gstart + 65;                        // [nedges]
    uintptr_t wp  = ((uintptr_t)(esrc + nedges) + 15) & ~(uintptr_t)15;
    unsigned short* wt1hi = (unsigned short*)wp;        // [128*512]
    unsigned short* wt1lo = wt1hi + 512 * 128;
    unsigned short* wt2hi = wt1lo + 512 * 128;          // [128*128]
    unsigned short* wt2lo = wt2hi + 128 * 128;

    dim3 blk(256);
    const int gNodes = (nnodes + 255) / 256;
    const int gEdges = (nedges + 255) / 256;
    const int gGemm  = (nnodes + 63) / 64;
    const int gAgg   = (nnodes + 3) / 4;
    const int nScanB = (nnodes + 1023) / 1024;

    // ---- graph preprocessing (CSR by dst + graph segments + W split) ----
    init_k<<<gNodes, blk, 0, stream>>>(cnt, nnodes);
    gstart_k<<<1, 128, 0, stream>>>(batch, gstart, nnodes, ngraphs);
    wprep_k<512><<<(512 * 128) / 256, blk, 0, stream>>>(W1, wt1hi, wt1lo);
    wprep_k<128><<<(128 * 128) / 256, blk, 0, stream>>>(W2, wt2hi, wt2lo);
    degcount_k<<<gEdges, blk, 0, stream>>>(dstp, cnt, nedges);
    dinv_k<<<gNodes, blk, 0, stream>>>(cnt, dinv, nnodes);
    scan1_k<<<nScanB, blk, 0, stream>>>(cnt, rowptr, bsum, nnodes);
    scan2_k<<<1, 64, 0, stream>>>(bsum, nScanB);
    scan3_k<<<nScanB, blk, 0, stream>>>(rowptr, cur, bsum, nnodes, nedges);
    fill_k<<<gEdges, blk, 0, stream>>>(srcp, dstp, cur, esrc, nedges);

    // ---- layer 1: MFMA GEMM + fused aggregate/BN/ReLU ----
    gemm_mfma_k<512><<<gGemm, blk, 0, stream>>>(x, wt1hi, wt1lo, wsA, nnodes);
    agg_k<<<gAgg, blk, 0, stream>>>(wsA, rowptr, esrc, dinv, b1, gamma1, beta1,
                                    rm1, rv1, wsB, nnodes);

    // ---- layer 2: MFMA GEMM + fused aggregate/BN/ReLU ----
    gemm_mfma_k<128><<<gGemm, blk, 0, stream>>>(wsB, wt2hi, wt2lo, wsA, nnodes);
    agg_k<<<gAgg, blk, 0, stream>>>(wsA, rowptr, esrc, dinv, b2, gamma2, beta2,
                                    rm2, rv2, wsB, nnodes);

    // ---- readout ----
    pool_k<<<ngraphs, blk, 0, stream>>>(wsB, gstart, pooled);
    final_k<<<1, 128, 0, stream>>>(pooled, Wl, bl, out);
}

// Round 5
// 435.197 us; speedup vs baseline: 1.2432x; 1.2432x over previous
//
#include <hip/hip_runtime.h>

#define EPSV 1e-5f

typedef __attribute__((ext_vector_type(8))) short short8;
typedef __attribute__((ext_vector_type(4))) float f32x4;

// ---------------- init: cnt=0 ----------------
__global__ __launch_bounds__(256) void init_k(int* __restrict__ cnt, int nnodes) {
    int i = blockIdx.x * 256 + threadIdx.x;
    if (i < nnodes) cnt[i] = 0;
}

// ---------------- graph segment starts via binary search on sorted batch ----
__global__ __launch_bounds__(128) void gstart_k(const int* __restrict__ batch,
                                                int* __restrict__ gstart,
                                                int nnodes, int ngraphs) {
    int g = threadIdx.x;
    if (g > ngraphs) return;
    int lo = 0, hi = nnodes;
    while (lo < hi) {
        int mid = (lo + hi) >> 1;
        if (batch[mid] < g) lo = mid + 1; else hi = mid;
    }
    gstart[g] = lo;
}

__global__ __launch_bounds__(256) void degcount_k(const int* __restrict__ dst,
                                                  int* __restrict__ cnt,
                                                  int nedges) {
    int i = blockIdx.x * 256 + threadIdx.x;
    if (i < nedges) atomicAdd(&cnt[dst[i]], 1);
}

__global__ __launch_bounds__(256) void dinv_k(const int* __restrict__ cnt,
                                              float* __restrict__ dinv, int nnodes) {
    int i = blockIdx.x * 256 + threadIdx.x;
    if (i < nnodes) dinv[i] = rsqrtf(1.0f + (float)cnt[i]);
}

// ---------------- exclusive scan of cnt[] -> rowptr[] ------------------------
__global__ __launch_bounds__(256) void scan1_k(const int* __restrict__ cnt,
                                               int* __restrict__ rowptr,
                                               int* __restrict__ bsum, int n) {
    __shared__ int sh[256];
    const int tx = threadIdx.x;
    const int base = blockIdx.x * 1024;
    int v[4];
    int s = 0;
#pragma unroll
    for (int j = 0; j < 4; j++) {
        int idx = base + tx * 4 + j;
        v[j] = (idx < n) ? cnt[idx] : 0;
        s += v[j];
    }
    sh[tx] = s;
    __syncthreads();
#pragma unroll
    for (int off = 1; off < 256; off <<= 1) {
        int t = (tx >= off) ? sh[tx - off] : 0;
        __syncthreads();
        sh[tx] += t;
        __syncthreads();
    }
    int run = sh[tx] - s;
#pragma unroll
    for (int j = 0; j < 4; j++) {
        int idx = base + tx * 4 + j;
        if (idx < n) rowptr[idx] = run;
        run += v[j];
    }
    if (tx == 255) bsum[blockIdx.x] = sh[255];
}

__global__ __launch_bounds__(64) void scan2_k(int* __restrict__ bsum, int nb) {
    __shared__ int sh[64];
    const int tx = threadIdx.x;
    int v = (tx < nb) ? bsum[tx] : 0;
    sh[tx] = v;
    __syncthreads();
#pragma unroll
    for (int off = 1; off < 64; off <<= 1) {
        int t = (tx >= off) ? sh[tx - off] : 0;
        __syncthreads();
        sh[tx] += t;
        __syncthreads();
    }
    if (tx < nb) bsum[tx] = sh[tx] - v;
}

__global__ __launch_bounds__(256) void scan3_k(int* __restrict__ rowptr,
                                               int* __restrict__ cur,
                                               const int* __restrict__ bsum,
                                               int n, int nedges) {
    const int tx = threadIdx.x;
    const int base = blockIdx.x * 1024;
    int off = bsum[blockIdx.x];
#pragma unroll
    for (int j = 0; j < 4; j++) {
        int idx = base + tx * 4 + j;
        if (idx < n) {
            int r = rowptr[idx] + off;
            rowptr[idx] = r;
            cur[idx] = r;
        }
    }
    if (blockIdx.x == 0 && tx == 0) rowptr[n] = nedges;
}

__global__ __launch_bounds__(256) void fill_k(const int* __restrict__ src,
                                              const int* __restrict__ dst,
                                              int* __restrict__ cur,
                                              int* __restrict__ esrc, int nedges) {
    int i = blockIdx.x * 256 + threadIdx.x;
    if (i >= nedges) return;
    int pos = atomicAdd(&cur[dst[i]], 1);
    esrc[pos] = src[i];
}

// ---------------- W prep: transpose + bf16 hi/lo split -----------------------
// wThi/wTlo[c][k] (ushort bf16 bits), c in [0,128), k in [0,K)
template <int K>
__global__ __launch_bounds__(256) void wprep_k(const float* __restrict__ W,
                                               unsigned short* __restrict__ wThi,
                                               unsigned short* __restrict__ wTlo) {
    int i = blockIdx.x * 256 + threadIdx.x;
    if (i >= K * 128) return;
    int k = i >> 7, c = i & 127;
    float x = W[i];
    unsigned u = __builtin_bit_cast(unsigned, x);
    unsigned short hi = (unsigned short)(u >> 16);
    float hif = __builtin_bit_cast(float, u & 0xffff0000u);
    float lof = x - hif;
    unsigned short lo = (unsigned short)(__builtin_bit_cast(unsigned, lof) >> 16);
    wThi[c * K + k] = hi;
    wTlo[c * K + k] = lo;
}

// ---------------- MFMA GEMM: H[nrows][128] = X[nrows][K] @ W[K][128] ---------
// Split-bf16: acc += xh*wh + xl*wh + xh*wl (fp32 acc).
// Block = 256 thr = 4 waves; wave owns 16 rows x 128 cols. B staged in LDS.
template <int K>
__global__ __launch_bounds__(256) void gemm_mfma_k(const float* __restrict__ X,
                                                   const unsigned short* __restrict__ wThi,
                                                   const unsigned short* __restrict__ wTlo,
                                                   float* __restrict__ H, int nrows) {
    // B tile for one BK=32 slice: [hilo][col 128][k 32 padded to 40]
    __shared__ unsigned short bsm[2][128][40];

    const int tx = threadIdx.x;
    const int wave = tx >> 6;
    const int l = tx & 63;
    const int lrow = l & 15;   // A-row in stripe / B-col within group / C-col
    const int kgrp = l >> 4;   // 0..3: k-subblock of 8
    const int row0 = blockIdx.x * 64 + wave * 16;

    int arow = row0 + lrow;
    if (arow >= nrows) arow = nrows - 1;   // clamp (duplicate load, store guarded)
    const float* xrow = X + (size_t)arow * K + kgrp * 8;

    f32x4 acc[8];
#pragma unroll
    for (int g = 0; g < 8; g++) acc[g] = (f32x4){0.f, 0.f, 0.f, 0.f};

    for (int k0 = 0; k0 < K; k0 += 32) {
        __syncthreads();   // previous-iter LDS reads done before overwrite
        // stage B hi+lo chunk: 2*128 rows * 32 k = 1024 16B-chunks; 4 per thread.
        // consecutive 4 threads read 64B contiguous global (kc 0/8/16/24).
#pragma unroll
        for (int r = 0; r < 4; r++) {
            int chunk = tx + r * 256;            // 0..1023
            int hilo = chunk >> 9;               // uniform per r
            int c = (chunk >> 2) & 127;
            int kc = (chunk & 3) * 8;
            const unsigned short* gsrc = (hilo ? wTlo : wThi) + (size_t)c * K + k0 + kc;
            short8 v = *reinterpret_cast<const short8*>(gsrc);
            *reinterpret_cast<short8*>(&bsm[hilo][c][kc]) = v;
        }
        __syncthreads();

        // A fragment: 8 contiguous f32 -> bf16 hi/lo (truncate; lo catches rest)
        f32x4 x0 = *reinterpret_cast<const f32x4*>(xrow + k0);
        f32x4 x1 = *reinterpret_cast<const f32x4*>(xrow + k0 + 4);
        short8 ah, al;
#pragma unroll
        for (int j = 0; j < 8; j++) {
            float f = (j < 4) ? x0[j] : x1[j - 4];
            unsigned u = __builtin_bit_cast(unsigned, f);
            ah[j] = (short)(u >> 16);
            float hif = __builtin_bit_cast(float, u & 0xffff0000u);
            float lof = f - hif;
            al[j] = (short)(__builtin_bit_cast(unsigned, lof) >> 16);
        }

#pragma unroll
        for (int g = 0; g < 8; g++) {
            short8 bh = *reinterpret_cast<const short8*>(&bsm[0][g * 16 + lrow][kgrp * 8]);
            short8 bl = *reinterpret_cast<const short8*>(&bsm[1][g * 16 + lrow][kgrp * 8]);
            acc[g] = __builtin_amdgcn_mfma_f32_16x16x32_bf16(ah, bh, acc[g], 0, 0, 0);
            acc[g] = __builtin_amdgcn_mfma_f32_16x16x32_bf16(al, bh, acc[g], 0, 0, 0);
            acc[g] = __builtin_amdgcn_mfma_f32_16x16x32_bf16(ah, bl, acc[g], 0, 0, 0);
        }
    }

    // C: row = row0 + kgrp*4 + r, col = g*16 + lrow  (verified m89 mapping)
#pragma unroll
    for (int r = 0; r < 4; r++) {
        int row = row0 + kgrp * 4 + r;
        if (row < nrows) {
            float* hrow = H + (size_t)row * 128 + lrow;
#pragma unroll
            for (int g = 0; g < 8; g++) hrow[g * 16] = acc[g][r];
        }
    }
}

// ---------------- fused aggregate: CSR gather + selfloop + bias + BN + ReLU --
__global__ __launch_bounds__(256) void agg_k(const float* __restrict__ H,
                                             const int* __restrict__ rowptr,
                                             const int* __restrict__ esrc,
                                             const float* __restrict__ dinv,
                                             const float* __restrict__ bias,
                                             const float* __restrict__ gamma,
                                             const float* __restrict__ beta,
                                             const float* __restrict__ rm,
                                             const float* __restrict__ rv,
                                             float* __restrict__ OUT,
                                             int nnodes) {
    const int node = blockIdx.x * 4 + (threadIdx.x >> 6);
    if (node >= nnodes) return;
    const int l = threadIdx.x & 63;
    const int c = l * 2;
    const float dn = dinv[node];

    float2 hv = *reinterpret_cast<const float2*>(H + (size_t)node * 128 + c);
    float2 acc = make_float2(hv.x * dn * dn, hv.y * dn * dn);
    float2 acc2 = make_float2(0.f, 0.f);

    const int beg = rowptr[node], end = rowptr[node + 1];
    int j = beg;
    for (; j + 1 < end; j += 2) {
        int s0 = esrc[j], s1 = esrc[j + 1];
        float n0 = dinv[s0] * dn, n1 = dinv[s1] * dn;
        float2 h0 = *reinterpret_cast<const float2*>(H + (size_t)s0 * 128 + c);
        float2 h1 = *reinterpret_cast<const float2*>(H + (size_t)s1 * 128 + c);
        acc.x += h0.x * n0;  acc.y += h0.y * n0;
        acc2.x += h1.x * n1; acc2.y += h1.y * n1;
    }
    if (j < end) {
        int s0 = esrc[j];
        float n0 = dinv[s0] * dn;
        float2 h0 = *reinterpret_cast<const float2*>(H + (size_t)s0 * 128 + c);
        acc.x += h0.x * n0; acc.y += h0.y * n0;
    }
    acc.x += acc2.x; acc.y += acc2.y;

    float v0 = acc.x + bias[c];
    float v1 = acc.y + bias[c + 1];
    v0 = (v0 - rm[c])     * rsqrtf(rv[c] + EPSV)     * gamma[c]     + beta[c];
    v1 = (v1 - rm[c + 1]) * rsqrtf(rv[c + 1] + EPSV) * gamma[c + 1] + beta[c + 1];
    v0 = fmaxf(v0, 0.0f);
    v1 = fmaxf(v1, 0.0f);

    *reinterpret_cast<float2*>(OUT + (size_t)node * 128 + c) = make_float2(v0, v1);
}

// ---------------- mean pool over contiguous graph segments ------------------
__global__ __launch_bounds__(256) void pool_k(const float* __restrict__ V,
                                              const int* __restrict__ gstart,
                                              float* __restrict__ pooled) {
    __shared__ float sh[256];
    const int g = blockIdx.x;
    const int tx = threadIdx.x;
    const int ch = tx & 127;
    const int sub = tx >> 7;
    const int beg = gstart[g], end = gstart[g + 1];
    float acc = 0.0f;
    for (int i = beg + sub; i < end; i += 2)
        acc += V[(size_t)i * 128 + ch];
    sh[tx] = acc;
    __syncthreads();
    if (tx < 128) {
        float tot = sh[tx] + sh[tx + 128];
        float cnt = fmaxf((float)(end - beg), 1.0f);
        pooled[g * 128 + tx] = tot / cnt;
    }
}

// ---------------- final: out[g][o] = pooled[g] @ Wl + bl ---------------------
__global__ __launch_bounds__(128) void final_k(const float* __restrict__ pooled,
                                               const float* __restrict__ Wl,
                                               const float* __restrict__ bl,
                                               float* __restrict__ out) {
    int tx = threadIdx.x;
    int g = tx >> 1, o = tx & 1;
    float s = 0.0f;
#pragma unroll 8
    for (int c = 0; c < 128; c++) s += pooled[g * 128 + c] * Wl[c * 2 + o];
    out[tx] = s + bl[o];
}

extern "C" void kernel_launch(void* const* d_in, const int* in_sizes, int n_in,
                              void* d_out, int out_size, void* d_ws, size_t ws_size,
                              hipStream_t stream) {
    const float* x      = (const float*)d_in[0];
    const int*   ei     = (const int*)d_in[1];
    const int*   batch  = (const int*)d_in[2];
    const float* W1     = (const float*)d_in[3];
    const float* b1     = (const float*)d_in[4];
    const float* gamma1 = (const float*)d_in[5];
    const float* beta1  = (const float*)d_in[6];
    const float* rm1    = (const float*)d_in[7];
    const float* rv1    = (const float*)d_in[8];
    const float* W2     = (const float*)d_in[9];
    const float* b2     = (const float*)d_in[10];
    const float* gamma2 = (const float*)d_in[11];
    const float* beta2  = (const float*)d_in[12];
    const float* rm2    = (const float*)d_in[13];
    const float* rv2    = (const float*)d_in[14];
    const float* Wl     = (const float*)d_in[15];
    const float* bl     = (const float*)d_in[16];
    float* out = (float*)d_out;

    const int nnodes  = in_sizes[2];
    const int nedges  = in_sizes[1] / 2;
    const int ngraphs = 64;
    const int* srcp = ei;
    const int* dstp = ei + nedges;

    float* wsA    = (float*)d_ws;                       // [nnodes*128]
    float* wsB    = wsA + (size_t)nnodes * 128;         // [nnodes*128]
    float* dinv   = wsB + (size_t)nnodes * 128;         // [nnodes]
    float* pooled = dinv + nnodes;                      // [64*128]
    int*   cnt    = (int*)(pooled + 64 * 128);          // [nnodes]
    int*   rowptr = cnt + nnodes;                       // [nnodes+1]
    int*   cur    = rowptr + nnodes + 1;                // [nnodes]
    int*   bsum   = cur + nnodes;                       // [64]
    int*   gstart = bsum + 64;                          // [65]
    int*   esrc   = gstart + 65;                        // [nedges]
    uintptr_t wp  = ((uintptr_t)(esrc + nedges) + 15) & ~(uintptr_t)15;
    unsigned short* wt1hi = (unsigned short*)wp;        // [128*512]
    unsigned short* wt1lo = wt1hi + 512 * 128;
    unsigned short* wt2hi = wt1lo + 512 * 128;          // [128*128]
    unsigned short* wt2lo = wt2hi + 128 * 128;

    dim3 blk(256);
    const int gNodes = (nnodes + 255) / 256;
    const int gEdges = (nedges + 255) / 256;
    const int gGemm  = (nnodes + 63) / 64;
    const int gAgg   = (nnodes + 3) / 4;
    const int nScanB = (nnodes + 1023) / 1024;

    // ---- graph preprocessing (CSR by dst + graph segments + W split) ----
    init_k<<<gNodes, blk, 0, stream>>>(cnt, nnodes);
    gstart_k<<<1, 128, 0, stream>>>(batch, gstart, nnodes, ngraphs);
    wprep_k<512><<<(512 * 128) / 256, blk, 0, stream>>>(W1, wt1hi, wt1lo);
    wprep_k<128><<<(128 * 128) / 256, blk, 0, stream>>>(W2, wt2hi, wt2lo);
    degcount_k<<<gEdges, blk, 0, stream>>>(dstp, cnt, nedges);
    dinv_k<<<gNodes, blk, 0, stream>>>(cnt, dinv, nnodes);
    scan1_k<<<nScanB, blk, 0, stream>>>(cnt, rowptr, bsum, nnodes);
    scan2_k<<<1, 64, 0, stream>>>(bsum, nScanB);
    scan3_k<<<nScanB, blk, 0, stream>>>(rowptr, cur, bsum, nnodes, nedges);
    fill_k<<<gEdges, blk, 0, stream>>>(srcp, dstp, cur, esrc, nedges);

    // ---- layer 1: MFMA GEMM + fused aggregate/BN/ReLU ----
    gemm_mfma_k<512><<<gGemm, blk, 0, stream>>>(x, wt1hi, wt1lo, wsA, nnodes);
    agg_k<<<gAgg, blk, 0, stream>>>(wsA, rowptr, esrc, dinv, b1, gamma1, beta1,
                                    rm1, rv1, wsB, nnodes);

    // ---- layer 2: MFMA GEMM + fused aggregate/BN/ReLU ----
    gemm_mfma_k<128><<<gGemm, blk, 0, stream>>>(wsB, wt2hi, wt2lo, wsA, nnodes);
    agg_k<<<gAgg, blk, 0, stream>>>(wsA, rowptr, esrc, dinv, b2, gamma2, beta2,
                                    rm2, rv2, wsB, nnodes);

    // ---- readout ----
    pool_k<<<ngraphs, blk, 0, stream>>>(wsB, gstart, pooled);
    final_k<<<1, 128, 0, stream>>>(pooled, Wl, bl, out);
}

// Round 6
// 341.304 us; speedup vs baseline: 1.5852x; 1.2751x over previous
//
#include <hip/hip_runtime.h>

#define EPSV 1e-5f

typedef __attribute__((ext_vector_type(8))) short short8;
typedef __attribute__((ext_vector_type(4))) float f32x4;

// ---------------- init: cnt=0 ----------------
__global__ __launch_bounds__(256) void init_k(int* __restrict__ cnt, int nnodes) {
    int i = blockIdx.x * 256 + threadIdx.x;
    if (i < nnodes) cnt[i] = 0;
}

// ---------------- graph segment starts via binary search on sorted batch ----
__global__ __launch_bounds__(128) void gstart_k(const int* __restrict__ batch,
                                                int* __restrict__ gstart,
                                                int nnodes, int ngraphs) {
    int g = threadIdx.x;
    if (g > ngraphs) return;
    int lo = 0, hi = nnodes;
    while (lo < hi) {
        int mid = (lo + hi) >> 1;
        if (batch[mid] < g) lo = mid + 1; else hi = mid;
    }
    gstart[g] = lo;
}

__global__ __launch_bounds__(256) void degcount_k(const int* __restrict__ dst,
                                                  int* __restrict__ cnt,
                                                  int nedges) {
    int i = blockIdx.x * 256 + threadIdx.x;
    if (i < nedges) atomicAdd(&cnt[dst[i]], 1);
}

__global__ __launch_bounds__(256) void dinv_k(const int* __restrict__ cnt,
                                              float* __restrict__ dinv, int nnodes) {
    int i = blockIdx.x * 256 + threadIdx.x;
    if (i < nnodes) dinv[i] = rsqrtf(1.0f + (float)cnt[i]);
}

// ---------------- exclusive scan of cnt[] -> rowptr[] ------------------------
__global__ __launch_bounds__(256) void scan1_k(const int* __restrict__ cnt,
                                               int* __restrict__ rowptr,
                                               int* __restrict__ bsum, int n) {
    __shared__ int sh[256];
    const int tx = threadIdx.x;
    const int base = blockIdx.x * 1024;
    int v[4];
    int s = 0;
#pragma unroll
    for (int j = 0; j < 4; j++) {
        int idx = base + tx * 4 + j;
        v[j] = (idx < n) ? cnt[idx] : 0;
        s += v[j];
    }
    sh[tx] = s;
    __syncthreads();
#pragma unroll
    for (int off = 1; off < 256; off <<= 1) {
        int t = (tx >= off) ? sh[tx - off] : 0;
        __syncthreads();
        sh[tx] += t;
        __syncthreads();
    }
    int run = sh[tx] - s;
#pragma unroll
    for (int j = 0; j < 4; j++) {
        int idx = base + tx * 4 + j;
        if (idx < n) rowptr[idx] = run;
        run += v[j];
    }
    if (tx == 255) bsum[blockIdx.x] = sh[255];
}

__global__ __launch_bounds__(64) void scan2_k(int* __restrict__ bsum, int nb) {
    __shared__ int sh[64];
    const int tx = threadIdx.x;
    int v = (tx < nb) ? bsum[tx] : 0;
    sh[tx] = v;
    __syncthreads();
#pragma unroll
    for (int off = 1; off < 64; off <<= 1) {
        int t = (tx >= off) ? sh[tx - off] : 0;
        __syncthreads();
        sh[tx] += t;
        __syncthreads();
    }
    if (tx < nb) bsum[tx] = sh[tx] - v;
}

__global__ __launch_bounds__(256) void scan3_k(int* __restrict__ rowptr,
                                               int* __restrict__ cur,
                                               const int* __restrict__ bsum,
                                               int n, int nedges) {
    const int tx = threadIdx.x;
    const int base = blockIdx.x * 1024;
    int off = bsum[blockIdx.x];
#pragma unroll
    for (int j = 0; j < 4; j++) {
        int idx = base + tx * 4 + j;
        if (idx < n) {
            int r = rowptr[idx] + off;
            rowptr[idx] = r;
            cur[idx] = r;
        }
    }
    if (blockIdx.x == 0 && tx == 0) rowptr[n] = nedges;
}

__global__ __launch_bounds__(256) void fill_k(const int* __restrict__ src,
                                              const int* __restrict__ dst,
                                              int* __restrict__ cur,
                                              int* __restrict__ esrc, int nedges) {
    int i = blockIdx.x * 256 + threadIdx.x;
    if (i >= nedges) return;
    int pos = atomicAdd(&cur[dst[i]], 1);
    esrc[pos] = src[i];
}

// ---------------- W prep: transpose + bf16 hi/lo split -----------------------
template <int K>
__global__ __launch_bounds__(256) void wprep_k(const float* __restrict__ W,
                                               unsigned short* __restrict__ wThi,
                                               unsigned short* __restrict__ wTlo) {
    int i = blockIdx.x * 256 + threadIdx.x;
    if (i >= K * 128) return;
    int k = i >> 7, c = i & 127;
    float x = W[i];
    unsigned u = __builtin_bit_cast(unsigned, x);
    unsigned short hi = (unsigned short)(u >> 16);
    float hif = __builtin_bit_cast(float, u & 0xffff0000u);
    float lof = x - hif;
    unsigned short lo = (unsigned short)(__builtin_bit_cast(unsigned, lof) >> 16);
    wThi[c * K + k] = hi;
    wTlo[c * K + k] = lo;
}

// ---------------- MFMA GEMM: H[nrows][128] = X[nrows][K] @ W[K][128] ---------
template <int K>
__global__ __launch_bounds__(256) void gemm_mfma_k(const float* __restrict__ X,
                                                   const unsigned short* __restrict__ wThi,
                                                   const unsigned short* __restrict__ wTlo,
                                                   float* __restrict__ H, int nrows) {
    __shared__ unsigned short bsm[2][128][40];

    const int tx = threadIdx.x;
    const int wave = tx >> 6;
    const int l = tx & 63;
    const int lrow = l & 15;
    const int kgrp = l >> 4;
    const int row0 = blockIdx.x * 64 + wave * 16;

    int arow = row0 + lrow;
    if (arow >= nrows) arow = nrows - 1;
    const float* xrow = X + (size_t)arow * K + kgrp * 8;

    f32x4 acc[8];
#pragma unroll
    for (int g = 0; g < 8; g++) acc[g] = (f32x4){0.f, 0.f, 0.f, 0.f};

    for (int k0 = 0; k0 < K; k0 += 32) {
        __syncthreads();
#pragma unroll
        for (int r = 0; r < 4; r++) {
            int chunk = tx + r * 256;
            int hilo = chunk >> 9;
            int c = (chunk >> 2) & 127;
            int kc = (chunk & 3) * 8;
            const unsigned short* gsrc = (hilo ? wTlo : wThi) + (size_t)c * K + k0 + kc;
            short8 v = *reinterpret_cast<const short8*>(gsrc);
            *reinterpret_cast<short8*>(&bsm[hilo][c][kc]) = v;
        }
        __syncthreads();

        f32x4 x0 = *reinterpret_cast<const f32x4*>(xrow + k0);
        f32x4 x1 = *reinterpret_cast<const f32x4*>(xrow + k0 + 4);
        short8 ah, al;
#pragma unroll
        for (int j = 0; j < 8; j++) {
            float f = (j < 4) ? x0[j] : x1[j - 4];
            unsigned u = __builtin_bit_cast(unsigned, f);
            ah[j] = (short)(u >> 16);
            float hif = __builtin_bit_cast(float, u & 0xffff0000u);
            float lof = f - hif;
            al[j] = (short)(__builtin_bit_cast(unsigned, lof) >> 16);
        }

#pragma unroll
        for (int g = 0; g < 8; g++) {
            short8 bh = *reinterpret_cast<const short8*>(&bsm[0][g * 16 + lrow][kgrp * 8]);
            short8 bl = *reinterpret_cast<const short8*>(&bsm[1][g * 16 + lrow][kgrp * 8]);
            acc[g] = __builtin_amdgcn_mfma_f32_16x16x32_bf16(ah, bh, acc[g], 0, 0, 0);
            acc[g] = __builtin_amdgcn_mfma_f32_16x16x32_bf16(al, bh, acc[g], 0, 0, 0);
            acc[g] = __builtin_amdgcn_mfma_f32_16x16x32_bf16(ah, bl, acc[g], 0, 0, 0);
        }
    }

#pragma unroll
    for (int r = 0; r < 4; r++) {
        int row = row0 + kgrp * 4 + r;
        if (row < nrows) {
            float* hrow = H + (size_t)row * 128 + lrow;
#pragma unroll
            for (int g = 0; g < 8; g++) hrow[g * 16] = acc[g][r];
        }
    }
}

// ---------------- fused aggregate: CSR gather + selfloop + bias + BN + ReLU --
__global__ __launch_bounds__(256) void agg_k(const float* __restrict__ H,
                                             const int* __restrict__ rowptr,
                                             const int* __restrict__ esrc,
                                             const float* __restrict__ dinv,
                                             const float* __restrict__ bias,
                                             const float* __restrict__ gamma,
                                             const float* __restrict__ beta,
                                             const float* __restrict__ rm,
                                             const float* __restrict__ rv,
                                             float* __restrict__ OUT,
                                             int nnodes) {
    const int node = blockIdx.x * 4 + (threadIdx.x >> 6);
    if (node >= nnodes) return;
    const int l = threadIdx.x & 63;
    const int c = l * 2;
    const float dn = dinv[node];

    float2 hv = *reinterpret_cast<const float2*>(H + (size_t)node * 128 + c);
    float2 acc = make_float2(hv.x * dn * dn, hv.y * dn * dn);
    float2 acc2 = make_float2(0.f, 0.f);

    const int beg = rowptr[node], end = rowptr[node + 1];
    int j = beg;
    for (; j + 1 < end; j += 2) {
        int s0 = esrc[j], s1 = esrc[j + 1];
        float n0 = dinv[s0] * dn, n1 = dinv[s1] * dn;
        float2 h0 = *reinterpret_cast<const float2*>(H + (size_t)s0 * 128 + c);
        float2 h1 = *reinterpret_cast<const float2*>(H + (size_t)s1 * 128 + c);
        acc.x += h0.x * n0;  acc.y += h0.y * n0;
        acc2.x += h1.x * n1; acc2.y += h1.y * n1;
    }
    if (j < end) {
        int s0 = esrc[j];
        float n0 = dinv[s0] * dn;
        float2 h0 = *reinterpret_cast<const float2*>(H + (size_t)s0 * 128 + c);
        acc.x += h0.x * n0; acc.y += h0.y * n0;
    }
    acc.x += acc2.x; acc.y += acc2.y;

    float v0 = acc.x + bias[c];
    float v1 = acc.y + bias[c + 1];
    v0 = (v0 - rm[c])     * rsqrtf(rv[c] + EPSV)     * gamma[c]     + beta[c];
    v1 = (v1 - rm[c + 1]) * rsqrtf(rv[c + 1] + EPSV) * gamma[c + 1] + beta[c + 1];
    v0 = fmaxf(v0, 0.0f);
    v1 = fmaxf(v1, 0.0f);

    *reinterpret_cast<float2*>(OUT + (size_t)node * 128 + c) = make_float2(v0, v1);
}

// ---------------- mean pool, stage 1: per-(graph, chunk) partial sums --------
// grid = ngraphs*32 blocks; 256 thr = 2 row-lanes x 128 channels
__global__ __launch_bounds__(256) void pool1_k(const float* __restrict__ V,
                                               const int* __restrict__ gstart,
                                               float* __restrict__ partial) {
    __shared__ float sh[256];
    const int g = blockIdx.x >> 5;
    const int p = blockIdx.x & 31;
    const int tx = threadIdx.x;
    const int ch = tx & 127;
    const int sub = tx >> 7;
    const int beg = gstart[g], end = gstart[g + 1];
    const int chunk = (end - beg + 31) >> 5;
    const int s = beg + p * chunk;
    const int e = min(s + chunk, end);
    float acc = 0.0f;
    for (int i = s + sub; i < e; i += 2)
        acc += V[(size_t)i * 128 + ch];
    sh[tx] = acc;
    __syncthreads();
    if (tx < 128)
        partial[(size_t)blockIdx.x * 128 + tx] = sh[tx] + sh[tx + 128];
}

// ---------------- mean pool, stage 2: reduce 32 partials, divide by count ----
__global__ __launch_bounds__(128) void pool2_k(const float* __restrict__ partial,
                                               const int* __restrict__ gstart,
                                               float* __restrict__ pooled) {
    const int g = blockIdx.x;
    const int ch = threadIdx.x;
    float s = 0.0f;
#pragma unroll
    for (int p = 0; p < 32; p++)
        s += partial[(size_t)((g << 5) + p) * 128 + ch];
    float cnt = fmaxf((float)(gstart[g + 1] - gstart[g]), 1.0f);
    pooled[g * 128 + ch] = s / cnt;
}

// ---------------- final: out[g][o] = pooled[g] @ Wl + bl ---------------------
__global__ __launch_bounds__(128) void final_k(const float* __restrict__ pooled,
                                               const float* __restrict__ Wl,
                                               const float* __restrict__ bl,
                                               float* __restrict__ out) {
    int tx = threadIdx.x;
    int g = tx >> 1, o = tx & 1;
    float s = 0.0f;
#pragma unroll 8
    for (int c = 0; c < 128; c++) s += pooled[g * 128 + c] * Wl[c * 2 + o];
    out[tx] = s + bl[o];
}

extern "C" void kernel_launch(void* const* d_in, const int* in_sizes, int n_in,
                              void* d_out, int out_size, void* d_ws, size_t ws_size,
                              hipStream_t stream) {
    const float* x      = (const float*)d_in[0];
    const int*   ei     = (const int*)d_in[1];
    const int*   batch  = (const int*)d_in[2];
    const float* W1     = (const float*)d_in[3];
    const float* b1     = (const float*)d_in[4];
    const float* gamma1 = (const float*)d_in[5];
    const float* beta1  = (const float*)d_in[6];
    const float* rm1    = (const float*)d_in[7];
    const float* rv1    = (const float*)d_in[8];
    const float* W2     = (const float*)d_in[9];
    const float* b2     = (const float*)d_in[10];
    const float* gamma2 = (const float*)d_in[11];
    const float* beta2  = (const float*)d_in[12];
    const float* rm2    = (const float*)d_in[13];
    const float* rv2    = (const float*)d_in[14];
    const float* Wl     = (const float*)d_in[15];
    const float* bl     = (const float*)d_in[16];
    float* out = (float*)d_out;

    const int nnodes  = in_sizes[2];
    const int nedges  = in_sizes[1] / 2;
    const int ngraphs = 64;
    const int* srcp = ei;
    const int* dstp = ei + nedges;

    float* wsA     = (float*)d_ws;                       // [nnodes*128]
    float* wsB     = wsA + (size_t)nnodes * 128;         // [nnodes*128]
    float* dinv    = wsB + (size_t)nnodes * 128;         // [nnodes]
    float* pooled  = dinv + nnodes;                      // [64*128]
    float* partial = pooled + 64 * 128;                  // [64*32*128]
    int*   cnt     = (int*)(partial + 64 * 32 * 128);    // [nnodes]
    int*   rowptr  = cnt + nnodes;                       // [nnodes+1]
    int*   cur     = rowptr + nnodes + 1;                // [nnodes]
    int*   bsum    = cur + nnodes;                       // [64]
    int*   gstart  = bsum + 64;                          // [65]
    int*   esrc    = gstart + 65;                        // [nedges]
    uintptr_t wp   = ((uintptr_t)(esrc + nedges) + 15) & ~(uintptr_t)15;
    unsigned short* wt1hi = (unsigned short*)wp;         // [128*512]
    unsigned short* wt1lo = wt1hi + 512 * 128;
    unsigned short* wt2hi = wt1lo + 512 * 128;           // [128*128]
    unsigned short* wt2lo = wt2hi + 128 * 128;

    dim3 blk(256);
    const int gNodes = (nnodes + 255) / 256;
    const int gEdges = (nedges + 255) / 256;
    const int gGemm  = (nnodes + 63) / 64;
    const int gAgg   = (nnodes + 3) / 4;
    const int nScanB = (nnodes + 1023) / 1024;

    // ---- graph preprocessing (CSR by dst + graph segments + W split) ----
    init_k<<<gNodes, blk, 0, stream>>>(cnt, nnodes);
    gstart_k<<<1, 128, 0, stream>>>(batch, gstart, nnodes, ngraphs);
    wprep_k<512><<<(512 * 128) / 256, blk, 0, stream>>>(W1, wt1hi, wt1lo);
    wprep_k<128><<<(128 * 128) / 256, blk, 0, stream>>>(W2, wt2hi, wt2lo);
    degcount_k<<<gEdges, blk, 0, stream>>>(dstp, cnt, nedges);
    dinv_k<<<gNodes, blk, 0, stream>>>(cnt, dinv, nnodes);
    scan1_k<<<nScanB, blk, 0, stream>>>(cnt, rowptr, bsum, nnodes);
    scan2_k<<<1, 64, 0, stream>>>(bsum, nScanB);
    scan3_k<<<nScanB, blk, 0, stream>>>(rowptr, cur, bsum, nnodes, nedges);
    fill_k<<<gEdges, blk, 0, stream>>>(srcp, dstp, cur, esrc, nedges);

    // ---- layer 1: MFMA GEMM + fused aggregate/BN/ReLU ----
    gemm_mfma_k<512><<<gGemm, blk, 0, stream>>>(x, wt1hi, wt1lo, wsA, nnodes);
    agg_k<<<gAgg, blk, 0, stream>>>(wsA, rowptr, esrc, dinv, b1, gamma1, beta1,
                                    rm1, rv1, wsB, nnodes);

    // ---- layer 2: MFMA GEMM + fused aggregate/BN/ReLU ----
    gemm_mfma_k<128><<<gGemm, blk, 0, stream>>>(wsB, wt2hi, wt2lo, wsA, nnodes);
    agg_k<<<gAgg, blk, 0, stream>>>(wsA, rowptr, esrc, dinv, b2, gamma2, beta2,
                                    rm2, rv2, wsB, nnodes);

    // ---- readout ----
    pool1_k<<<ngraphs * 32, blk, 0, stream>>>(wsB, gstart, partial);
    pool2_k<<<ngraphs, 128, 0, stream>>>(partial, gstart, pooled);
    final_k<<<1, 128, 0, stream>>>(pooled, Wl, bl, out);
}

// Round 7
// 287.690 us; speedup vs baseline: 1.8806x; 1.1864x over previous
//
#include <hip/hip_runtime.h>

#define EPSV 1e-5f

typedef __attribute__((ext_vector_type(8))) short short8;
typedef __attribute__((ext_vector_type(4))) float f32x4;
typedef unsigned int uint;

// ---------------- init: cnt=0 ----------------
__global__ __launch_bounds__(256) void init_k(int* __restrict__ cnt, int nnodes) {
    int i = blockIdx.x * 256 + threadIdx.x;
    if (i < nnodes) cnt[i] = 0;
}

// ---------------- graph segment starts via binary search on sorted batch ----
__global__ __launch_bounds__(128) void gstart_k(const int* __restrict__ batch,
                                                int* __restrict__ gstart,
                                                int nnodes, int ngraphs) {
    int g = threadIdx.x;
    if (g > ngraphs) return;
    int lo = 0, hi = nnodes;
    while (lo < hi) {
        int mid = (lo + hi) >> 1;
        if (batch[mid] < g) lo = mid + 1; else hi = mid;
    }
    gstart[g] = lo;
}

__global__ __launch_bounds__(256) void degcount_k(const int* __restrict__ dst,
                                                  int* __restrict__ cnt,
                                                  int nedges) {
    int i = blockIdx.x * 256 + threadIdx.x;
    if (i < nedges) atomicAdd(&cnt[dst[i]], 1);
}

__global__ __launch_bounds__(256) void dinv_k(const int* __restrict__ cnt,
                                              float* __restrict__ dinv, int nnodes) {
    int i = blockIdx.x * 256 + threadIdx.x;
    if (i < nnodes) dinv[i] = rsqrtf(1.0f + (float)cnt[i]);
}

// ---------------- exclusive scan of cnt[] -> rowptr[] ------------------------
__global__ __launch_bounds__(256) void scan1_k(const int* __restrict__ cnt,
                                               int* __restrict__ rowptr,
                                               int* __restrict__ bsum, int n) {
    __shared__ int sh[256];
    const int tx = threadIdx.x;
    const int base = blockIdx.x * 1024;
    int v[4];
    int s = 0;
#pragma unroll
    for (int j = 0; j < 4; j++) {
        int idx = base + tx * 4 + j;
        v[j] = (idx < n) ? cnt[idx] : 0;
        s += v[j];
    }
    sh[tx] = s;
    __syncthreads();
#pragma unroll
    for (int off = 1; off < 256; off <<= 1) {
        int t = (tx >= off) ? sh[tx - off] : 0;
        __syncthreads();
        sh[tx] += t;
        __syncthreads();
    }
    int run = sh[tx] - s;
#pragma unroll
    for (int j = 0; j < 4; j++) {
        int idx = base + tx * 4 + j;
        if (idx < n) rowptr[idx] = run;
        run += v[j];
    }
    if (tx == 255) bsum[blockIdx.x] = sh[255];
}

__global__ __launch_bounds__(64) void scan2_k(int* __restrict__ bsum, int nb) {
    __shared__ int sh[64];
    const int tx = threadIdx.x;
    int v = (tx < nb) ? bsum[tx] : 0;
    sh[tx] = v;
    __syncthreads();
#pragma unroll
    for (int off = 1; off < 64; off <<= 1) {
        int t = (tx >= off) ? sh[tx - off] : 0;
        __syncthreads();
        sh[tx] += t;
        __syncthreads();
    }
    if (tx < nb) bsum[tx] = sh[tx] - v;
}

__global__ __launch_bounds__(256) void scan3_k(int* __restrict__ rowptr,
                                               int* __restrict__ cur,
                                               const int* __restrict__ bsum,
                                               int n, int nedges) {
    const int tx = threadIdx.x;
    const int base = blockIdx.x * 1024;
    int off = bsum[blockIdx.x];
#pragma unroll
    for (int j = 0; j < 4; j++) {
        int idx = base + tx * 4 + j;
        if (idx < n) {
            int r = rowptr[idx] + off;
            rowptr[idx] = r;
            cur[idx] = r;
        }
    }
    if (blockIdx.x == 0 && tx == 0) rowptr[n] = nedges;
}

__global__ __launch_bounds__(256) void fill_k(const int* __restrict__ src,
                                              const int* __restrict__ dst,
                                              int* __restrict__ cur,
                                              int* __restrict__ esrc, int nedges) {
    int i = blockIdx.x * 256 + threadIdx.x;
    if (i >= nedges) return;
    int pos = atomicAdd(&cur[dst[i]], 1);
    esrc[pos] = src[i];
}

// ---------------- W prep: transpose + bf16 hi/lo split -----------------------
template <int K>
__global__ __launch_bounds__(256) void wprep_k(const float* __restrict__ W,
                                               unsigned short* __restrict__ wThi,
                                               unsigned short* __restrict__ wTlo) {
    int i = blockIdx.x * 256 + threadIdx.x;
    if (i >= K * 128) return;
    int k = i >> 7, c = i & 127;
    float x = W[i];
    unsigned u = __builtin_bit_cast(unsigned, x);
    unsigned short hi = (unsigned short)(u >> 16);
    float hif = __builtin_bit_cast(float, u & 0xffff0000u);
    float lof = x - hif;
    unsigned short lo = (unsigned short)(__builtin_bit_cast(unsigned, lof) >> 16);
    wThi[c * K + k] = hi;
    wTlo[c * K + k] = lo;
}

// ---------------- MFMA GEMM: H[nrows][128] = X[nrows][K] @ W[K][128] ---------
template <int K>
__global__ __launch_bounds__(256) void gemm_mfma_k(const float* __restrict__ X,
                                                   const unsigned short* __restrict__ wThi,
                                                   const unsigned short* __restrict__ wTlo,
                                                   float* __restrict__ H, int nrows) {
    __shared__ unsigned short bsm[2][128][40];

    const int tx = threadIdx.x;
    const int wave = tx >> 6;
    const int l = tx & 63;
    const int lrow = l & 15;
    const int kgrp = l >> 4;
    const int row0 = blockIdx.x * 64 + wave * 16;

    int arow = row0 + lrow;
    if (arow >= nrows) arow = nrows - 1;
    const float* xrow = X + (size_t)arow * K + kgrp * 8;

    f32x4 acc[8];
#pragma unroll
    for (int g = 0; g < 8; g++) acc[g] = (f32x4){0.f, 0.f, 0.f, 0.f};

    for (int k0 = 0; k0 < K; k0 += 32) {
        __syncthreads();
#pragma unroll
        for (int r = 0; r < 4; r++) {
            int chunk = tx + r * 256;
            int hilo = chunk >> 9;
            int c = (chunk >> 2) & 127;
            int kc = (chunk & 3) * 8;
            const unsigned short* gsrc = (hilo ? wTlo : wThi) + (size_t)c * K + k0 + kc;
            short8 v = *reinterpret_cast<const short8*>(gsrc);
            *reinterpret_cast<short8*>(&bsm[hilo][c][kc]) = v;
        }
        __syncthreads();

        f32x4 x0 = *reinterpret_cast<const f32x4*>(xrow + k0);
        f32x4 x1 = *reinterpret_cast<const f32x4*>(xrow + k0 + 4);
        short8 ah, al;
#pragma unroll
        for (int j = 0; j < 8; j++) {
            float f = (j < 4) ? x0[j] : x1[j - 4];
            unsigned u = __builtin_bit_cast(unsigned, f);
            ah[j] = (short)(u >> 16);
            float hif = __builtin_bit_cast(float, u & 0xffff0000u);
            float lof = f - hif;
            al[j] = (short)(__builtin_bit_cast(unsigned, lof) >> 16);
        }

#pragma unroll
        for (int g = 0; g < 8; g++) {
            short8 bh = *reinterpret_cast<const short8*>(&bsm[0][g * 16 + lrow][kgrp * 8]);
            short8 bl = *reinterpret_cast<const short8*>(&bsm[1][g * 16 + lrow][kgrp * 8]);
            acc[g] = __builtin_amdgcn_mfma_f32_16x16x32_bf16(ah, bh, acc[g], 0, 0, 0);
            acc[g] = __builtin_amdgcn_mfma_f32_16x16x32_bf16(al, bh, acc[g], 0, 0, 0);
            acc[g] = __builtin_amdgcn_mfma_f32_16x16x32_bf16(ah, bl, acc[g], 0, 0, 0);
        }
    }

#pragma unroll
    for (int r = 0; r < 4; r++) {
        int row = row0 + kgrp * 4 + r;
        if (row < nrows) {
            float* hrow = H + (size_t)row * 128 + lrow;
#pragma unroll
            for (int g = 0; g < 8; g++) hrow[g * 16] = acc[g][r];
        }
    }
}

// ---------------- scale: hb[i][c] = bf16_rne(H[i][c] * dinv[i]), packed x2 ----
// thread handles 4 channels: reads float4, writes uint2 (2 packed bf16 pairs)
__global__ __launch_bounds__(256) void scale_k(const float* __restrict__ H,
                                               const float* __restrict__ dinv,
                                               uint* __restrict__ hb, int nfeat4) {
    int i = blockIdx.x * 256 + threadIdx.x;
    if (i >= nfeat4) return;
    float dn = dinv[i >> 5];                    // 32 float4 groups per node
    f32x4 v = *reinterpret_cast<const f32x4*>(H + (size_t)i * 4);
    uint b[4];
#pragma unroll
    for (int j = 0; j < 4; j++) {
        unsigned u = __builtin_bit_cast(unsigned, v[j] * dn);
        b[j] = u + 0x7fffu + ((u >> 16) & 1u);  // RNE to bf16
    }
    uint2 o;
    o.x = (b[0] >> 16) | (b[1] & 0xffff0000u);
    o.y = (b[2] >> 16) | (b[3] & 0xffff0000u);
    *reinterpret_cast<uint2*>(hb + (size_t)i * 2) = o;
}

// ------ fused aggregate: out[d] = dinv[d]*(h[d]*dinv[d] + sum hb[src]) -------
// then bias + BN(eval) + ReLU.  One 64-lane wave per node, 4 B/lane gathers.
__global__ __launch_bounds__(256) void agg_k(const float* __restrict__ H,
                                             const uint* __restrict__ hb,
                                             const int* __restrict__ rowptr,
                                             const int* __restrict__ esrc,
                                             const float* __restrict__ dinv,
                                             const float* __restrict__ bias,
                                             const float* __restrict__ gamma,
                                             const float* __restrict__ beta,
                                             const float* __restrict__ rm,
                                             const float* __restrict__ rv,
                                             float* __restrict__ OUT,
                                             int nnodes) {
    int node = blockIdx.x * 4 + (threadIdx.x >> 6);
    if (node >= nnodes) return;
    node = __builtin_amdgcn_readfirstlane(node);
    const int l = threadIdx.x & 63;
    const int c = l * 2;
    const float dn = dinv[node];
    const int beg = rowptr[node], end = rowptr[node + 1];

    float2 hv = *reinterpret_cast<const float2*>(H + (size_t)node * 128 + c);
    float ax0 = hv.x * dn, ay0 = hv.y * dn;     // self-loop term (x dn later)
    float ax1 = 0.f, ay1 = 0.f, ax2 = 0.f, ay2 = 0.f, ax3 = 0.f, ay3 = 0.f;
    const uint* hbl = hb + l;

    int j = beg;
    for (; j + 3 < end; j += 4) {
        int s0 = esrc[j], s1 = esrc[j + 1], s2 = esrc[j + 2], s3 = esrc[j + 3];
        uint u0 = hbl[(size_t)s0 * 64];
        uint u1 = hbl[(size_t)s1 * 64];
        uint u2 = hbl[(size_t)s2 * 64];
        uint u3 = hbl[(size_t)s3 * 64];
        ax0 += __builtin_bit_cast(float, u0 << 16);
        ay0 += __builtin_bit_cast(float, u0 & 0xffff0000u);
        ax1 += __builtin_bit_cast(float, u1 << 16);
        ay1 += __builtin_bit_cast(float, u1 & 0xffff0000u);
        ax2 += __builtin_bit_cast(float, u2 << 16);
        ay2 += __builtin_bit_cast(float, u2 & 0xffff0000u);
        ax3 += __builtin_bit_cast(float, u3 << 16);
        ay3 += __builtin_bit_cast(float, u3 & 0xffff0000u);
    }
    for (; j < end; j++) {
        uint u0 = hbl[(size_t)esrc[j] * 64];
        ax0 += __builtin_bit_cast(float, u0 << 16);
        ay0 += __builtin_bit_cast(float, u0 & 0xffff0000u);
    }
    float accx = (ax0 + ax1) + (ax2 + ax3);
    float accy = (ay0 + ay1) + (ay2 + ay3);

    float v0 = accx * dn + bias[c];
    float v1 = accy * dn + bias[c + 1];
    v0 = (v0 - rm[c])     * rsqrtf(rv[c] + EPSV)     * gamma[c]     + beta[c];
    v1 = (v1 - rm[c + 1]) * rsqrtf(rv[c + 1] + EPSV) * gamma[c + 1] + beta[c + 1];
    v0 = fmaxf(v0, 0.0f);
    v1 = fmaxf(v1, 0.0f);

    *reinterpret_cast<float2*>(OUT + (size_t)node * 128 + c) = make_float2(v0, v1);
}

// ---------------- mean pool, stage 1: per-(graph, chunk) partial sums --------
__global__ __launch_bounds__(256) void pool1_k(const float* __restrict__ V,
                                               const int* __restrict__ gstart,
                                               float* __restrict__ partial) {
    __shared__ float sh[256];
    const int g = blockIdx.x >> 5;
    const int p = blockIdx.x & 31;
    const int tx = threadIdx.x;
    const int ch = tx & 127;
    const int sub = tx >> 7;
    const int beg = gstart[g], end = gstart[g + 1];
    const int chunk = (end - beg + 31) >> 5;
    const int s = beg + p * chunk;
    const int e = min(s + chunk, end);
    float acc = 0.0f;
    for (int i = s + sub; i < e; i += 2)
        acc += V[(size_t)i * 128 + ch];
    sh[tx] = acc;
    __syncthreads();
    if (tx < 128)
        partial[(size_t)blockIdx.x * 128 + tx] = sh[tx] + sh[tx + 128];
}

// ---------------- mean pool, stage 2 -----------------------------------------
__global__ __launch_bounds__(128) void pool2_k(const float* __restrict__ partial,
                                               const int* __restrict__ gstart,
                                               float* __restrict__ pooled) {
    const int g = blockIdx.x;
    const int ch = threadIdx.x;
    float s = 0.0f;
#pragma unroll
    for (int p = 0; p < 32; p++)
        s += partial[(size_t)((g << 5) + p) * 128 + ch];
    float cnt = fmaxf((float)(gstart[g + 1] - gstart[g]), 1.0f);
    pooled[g * 128 + ch] = s / cnt;
}

// ---------------- final: out[g][o] = pooled[g] @ Wl + bl ---------------------
__global__ __launch_bounds__(128) void final_k(const float* __restrict__ pooled,
                                               const float* __restrict__ Wl,
                                               const float* __restrict__ bl,
                                               float* __restrict__ out) {
    int tx = threadIdx.x;
    int g = tx >> 1, o = tx & 1;
    float s = 0.0f;
#pragma unroll 8
    for (int c = 0; c < 128; c++) s += pooled[g * 128 + c] * Wl[c * 2 + o];
    out[tx] = s + bl[o];
}

extern "C" void kernel_launch(void* const* d_in, const int* in_sizes, int n_in,
                              void* d_out, int out_size, void* d_ws, size_t ws_size,
                              hipStream_t stream) {
    const float* x      = (const float*)d_in[0];
    const int*   ei     = (const int*)d_in[1];
    const int*   batch  = (const int*)d_in[2];
    const float* W1     = (const float*)d_in[3];
    const float* b1     = (const float*)d_in[4];
    const float* gamma1 = (const float*)d_in[5];
    const float* beta1  = (const float*)d_in[6];
    const float* rm1    = (const float*)d_in[7];
    const float* rv1    = (const float*)d_in[8];
    const float* W2     = (const float*)d_in[9];
    const float* b2     = (const float*)d_in[10];
    const float* gamma2 = (const float*)d_in[11];
    const float* beta2  = (const float*)d_in[12];
    const float* rm2    = (const float*)d_in[13];
    const float* rv2    = (const float*)d_in[14];
    const float* Wl     = (const float*)d_in[15];
    const float* bl     = (const float*)d_in[16];
    float* out = (float*)d_out;

    const int nnodes  = in_sizes[2];
    const int nedges  = in_sizes[1] / 2;
    const int ngraphs = 64;
    const int* srcp = ei;
    const int* dstp = ei + nedges;

    float* wsA     = (float*)d_ws;                       // [nnodes*128]
    float* wsB     = wsA + (size_t)nnodes * 128;         // [nnodes*128]
    float* dinv    = wsB + (size_t)nnodes * 128;         // [nnodes]
    float* pooled  = dinv + nnodes;                      // [64*128]
    float* partial = pooled + 64 * 128;                  // [64*32*128]
    int*   cnt     = (int*)(partial + 64 * 32 * 128);    // [nnodes]
    int*   rowptr  = cnt + nnodes;                       // [nnodes+1]
    int*   cur     = rowptr + nnodes + 1;                // [nnodes]
    int*   bsum    = cur + nnodes;                       // [64]
    int*   gstart  = bsum + 64;                          // [65]
    int*   esrc    = gstart + 65;                        // [nedges]
    uintptr_t wp   = ((uintptr_t)(esrc + nedges) + 15) & ~(uintptr_t)15;
    unsigned short* wt1hi = (unsigned short*)wp;         // [128*512]
    unsigned short* wt1lo = wt1hi + 512 * 128;
    unsigned short* wt2hi = wt1lo + 512 * 128;           // [128*128]
    unsigned short* wt2lo = wt2hi + 128 * 128;
    uint* hb = (uint*)(wt2lo + 128 * 128);               // [nnodes*64] packed bf16

    dim3 blk(256);
    const int gNodes = (nnodes + 255) / 256;
    const int gEdges = (nedges + 255) / 256;
    const int gGemm  = (nnodes + 63) / 64;
    const int gAgg   = (nnodes + 3) / 4;
    const int nScanB = (nnodes + 1023) / 1024;
    const int nfeat4 = nnodes * 32;                      // float4 groups
    const int gScale = (nfeat4 + 255) / 256;

    // ---- graph preprocessing (CSR by dst + graph segments + W split) ----
    init_k<<<gNodes, blk, 0, stream>>>(cnt, nnodes);
    gstart_k<<<1, 128, 0, stream>>>(batch, gstart, nnodes, ngraphs);
    wprep_k<512><<<(512 * 128) / 256, blk, 0, stream>>>(W1, wt1hi, wt1lo);
    wprep_k<128><<<(128 * 128) / 256, blk, 0, stream>>>(W2, wt2hi, wt2lo);
    degcount_k<<<gEdges, blk, 0, stream>>>(dstp, cnt, nedges);
    dinv_k<<<gNodes, blk, 0, stream>>>(cnt, dinv, nnodes);
    scan1_k<<<nScanB, blk, 0, stream>>>(cnt, rowptr, bsum, nnodes);
    scan2_k<<<1, 64, 0, stream>>>(bsum, nScanB);
    scan3_k<<<nScanB, blk, 0, stream>>>(rowptr, cur, bsum, nnodes, nedges);
    fill_k<<<gEdges, blk, 0, stream>>>(srcp, dstp, cur, esrc, nedges);

    // ---- layer 1 ----
    gemm_mfma_k<512><<<gGemm, blk, 0, stream>>>(x, wt1hi, wt1lo, wsA, nnodes);
    scale_k<<<gScale, blk, 0, stream>>>(wsA, dinv, hb, nfeat4);
    agg_k<<<gAgg, blk, 0, stream>>>(wsA, hb, rowptr, esrc, dinv, b1, gamma1, beta1,
                                    rm1, rv1, wsB, nnodes);

    // ---- layer 2 ----
    gemm_mfma_k<128><<<gGemm, blk, 0, stream>>>(wsB, wt2hi, wt2lo, wsA, nnodes);
    scale_k<<<gScale, blk, 0, stream>>>(wsA, dinv, hb, nfeat4);
    agg_k<<<gAgg, blk, 0, stream>>>(wsA, hb, rowptr, esrc, dinv, b2, gamma2, beta2,
                                    rm2, rv2, wsB, nnodes);

    // ---- readout ----
    pool1_k<<<ngraphs * 32, blk, 0, stream>>>(wsB, gstart, partial);
    pool2_k<<<ngraphs, 128, 0, stream>>>(partial, gstart, pooled);
    final_k<<<1, 128, 0, stream>>>(pooled, Wl, bl, out);
}

// Round 8
// 280.294 us; speedup vs baseline: 1.9302x; 1.0264x over previous
//
#include <hip/hip_runtime.h>

#define EPSV 1e-5f

typedef __attribute__((ext_vector_type(8))) short short8;
typedef __attribute__((ext_vector_type(4))) float f32x4;
typedef unsigned int uint;
typedef unsigned short ushort;

// ---------------- init: cnt=0 ----------------
__global__ __launch_bounds__(256) void init_k(int* __restrict__ cnt, int nnodes) {
    int i = blockIdx.x * 256 + threadIdx.x;
    if (i < nnodes) cnt[i] = 0;
}

// ---------------- graph segment starts via binary search on sorted batch ----
__global__ __launch_bounds__(128) void gstart_k(const int* __restrict__ batch,
                                                int* __restrict__ gstart,
                                                int nnodes, int ngraphs) {
    int g = threadIdx.x;
    if (g > ngraphs) return;
    int lo = 0, hi = nnodes;
    while (lo < hi) {
        int mid = (lo + hi) >> 1;
        if (batch[mid] < g) lo = mid + 1; else hi = mid;
    }
    gstart[g] = lo;
}

__global__ __launch_bounds__(256) void degcount_k(const int* __restrict__ dst,
                                                  int* __restrict__ cnt,
                                                  int nedges) {
    int i = blockIdx.x * 256 + threadIdx.x;
    if (i < nedges) atomicAdd(&cnt[dst[i]], 1);
}

__global__ __launch_bounds__(256) void dinv_k(const int* __restrict__ cnt,
                                              float* __restrict__ dinv, int nnodes) {
    int i = blockIdx.x * 256 + threadIdx.x;
    if (i < nnodes) dinv[i] = rsqrtf(1.0f + (float)cnt[i]);
}

// ---------------- exclusive scan of cnt[] -> rowptr[] ------------------------
__global__ __launch_bounds__(256) void scan1_k(const int* __restrict__ cnt,
                                               int* __restrict__ rowptr,
                                               int* __restrict__ bsum, int n) {
    __shared__ int sh[256];
    const int tx = threadIdx.x;
    const int base = blockIdx.x * 1024;
    int v[4];
    int s = 0;
#pragma unroll
    for (int j = 0; j < 4; j++) {
        int idx = base + tx * 4 + j;
        v[j] = (idx < n) ? cnt[idx] : 0;
        s += v[j];
    }
    sh[tx] = s;
    __syncthreads();
#pragma unroll
    for (int off = 1; off < 256; off <<= 1) {
        int t = (tx >= off) ? sh[tx - off] : 0;
        __syncthreads();
        sh[tx] += t;
        __syncthreads();
    }
    int run = sh[tx] - s;
#pragma unroll
    for (int j = 0; j < 4; j++) {
        int idx = base + tx * 4 + j;
        if (idx < n) rowptr[idx] = run;
        run += v[j];
    }
    if (tx == 255) bsum[blockIdx.x] = sh[255];
}

__global__ __launch_bounds__(64) void scan2_k(int* __restrict__ bsum, int nb) {
    __shared__ int sh[64];
    const int tx = threadIdx.x;
    int v = (tx < nb) ? bsum[tx] : 0;
    sh[tx] = v;
    __syncthreads();
#pragma unroll
    for (int off = 1; off < 64; off <<= 1) {
        int t = (tx >= off) ? sh[tx - off] : 0;
        __syncthreads();
        sh[tx] += t;
        __syncthreads();
    }
    if (tx < nb) bsum[tx] = sh[tx] - v;
}

__global__ __launch_bounds__(256) void scan3_k(int* __restrict__ rowptr,
                                               int* __restrict__ cur,
                                               const int* __restrict__ bsum,
                                               int n, int nedges) {
    const int tx = threadIdx.x;
    const int base = blockIdx.x * 1024;
    int off = bsum[blockIdx.x];
#pragma unroll
    for (int j = 0; j < 4; j++) {
        int idx = base + tx * 4 + j;
        if (idx < n) {
            int r = rowptr[idx] + off;
            rowptr[idx] = r;
            cur[idx] = r;
        }
    }
    if (blockIdx.x == 0 && tx == 0) rowptr[n] = nedges;
}

__global__ __launch_bounds__(256) void fill_k(const int* __restrict__ src,
                                              const int* __restrict__ dst,
                                              int* __restrict__ cur,
                                              int* __restrict__ esrc, int nedges) {
    int i = blockIdx.x * 256 + threadIdx.x;
    if (i >= nedges) return;
    int pos = atomicAdd(&cur[dst[i]], 1);
    esrc[pos] = src[i];
}

// ---------------- W prep: transpose + bf16 hi/lo split -----------------------
template <int K>
__global__ __launch_bounds__(256) void wprep_k(const float* __restrict__ W,
                                               ushort* __restrict__ wThi,
                                               ushort* __restrict__ wTlo) {
    int i = blockIdx.x * 256 + threadIdx.x;
    if (i >= K * 128) return;
    int k = i >> 7, c = i & 127;
    float x = W[i];
    unsigned u = __builtin_bit_cast(unsigned, x);
    ushort hi = (ushort)(u >> 16);
    float hif = __builtin_bit_cast(float, u & 0xffff0000u);
    float lof = x - hif;
    ushort lo = (ushort)(__builtin_bit_cast(unsigned, lof) >> 16);
    wThi[c * K + k] = hi;
    wTlo[c * K + k] = lo;
}

// ---------------- MFMA GEMM: H = X @ W, + fused hb = bf16(H*dinv) -----------
// Split-bf16: acc += xh*wh + xl*wh + xh*wl (fp32 acc).
// 256 thr = 4 waves; wave owns 16 rows x 128 cols. B double-buffered in LDS
// via global_load_lds with XOR-swizzled source (linear LDS dest).
// LDS layout per buffer: c-row = 128B = 8 x 16B slots; unswizzled slot s:
//   s=0..3 -> hi k-chunk s, s=4..7 -> lo k-chunk s-4; stored at s' = s ^ (c&7).
template <int K>
__global__ __launch_bounds__(256) void gemm_mfma_k(const float* __restrict__ X,
                                                   const ushort* __restrict__ wThi,
                                                   const ushort* __restrict__ wTlo,
                                                   const float* __restrict__ dinv,
                                                   float* __restrict__ H,
                                                   ushort* __restrict__ hb16,
                                                   int nrows) {
    __shared__ ushort bsm[2][8192];   // 2 x 16 KB

    const int tx = threadIdx.x;
    const int wu = __builtin_amdgcn_readfirstlane(tx >> 6);   // wave id (uniform)
    const int l = tx & 63;
    const int lrow = l & 15;
    const int kgrp = l >> 4;
    const int row0 = blockIdx.x * 64 + wu * 16;

    // staging source pointers (per-lane, pre-swizzled)
    const ushort* sp[4];
#pragma unroll
    for (int q = 0; q < 4; q++) {
        int chunk = (wu * 4 + q) * 64 + l;       // 16B-chunk id in slice
        int c = chunk >> 3;
        int sl = (chunk & 7) ^ (c & 7);          // unswizzled slot
        sp[q] = ((sl >> 2) ? wTlo : wThi) + (size_t)c * K + (sl & 3) * 8;
    }

    int arow = row0 + lrow;
    if (arow >= nrows) arow = nrows - 1;         // clamp (store guarded)
    const float* xrow = X + (size_t)arow * K + kgrp * 8;

    f32x4 acc[8];
#pragma unroll
    for (int g = 0; g < 8; g++) acc[g] = (f32x4){0.f, 0.f, 0.f, 0.f};

    auto STAGE = [&](int buf, int k0) {
#pragma unroll
        for (int q = 0; q < 4; q++) {
            const ushort* src = sp[q] + k0;
            ushort* dst = &bsm[buf][(wu * 4 + q) * 512];   // +lane*16B by HW
            __builtin_amdgcn_global_load_lds(
                (const __attribute__((address_space(1))) unsigned int*)(const void*)src,
                (__attribute__((address_space(3))) unsigned int*)(void*)dst,
                16, 0, 0);
        }
    };

    constexpr int NIT = K / 32;
    STAGE(0, 0);
    f32x4 xa = *reinterpret_cast<const f32x4*>(xrow);
    f32x4 xb = *reinterpret_cast<const f32x4*>(xrow + 4);
    __syncthreads();                             // buf0 staged (vmcnt drain)

    for (int i = 0; i < NIT; i++) {
        const int cur = i & 1;
        if (i + 1 < NIT) STAGE(cur ^ 1, (i + 1) * 32);
        f32x4 na = xa, nb = xb;
        if (i + 1 < NIT) {
            na = *reinterpret_cast<const f32x4*>(xrow + (i + 1) * 32);
            nb = *reinterpret_cast<const f32x4*>(xrow + (i + 1) * 32 + 4);
        }

        // A fragment: 8 contiguous f32 -> bf16 hi/lo (truncate; lo catches rest)
        short8 ah, al;
#pragma unroll
        for (int j = 0; j < 8; j++) {
            float f = (j < 4) ? xa[j] : xb[j - 4];
            unsigned u = __builtin_bit_cast(unsigned, f);
            ah[j] = (short)(u >> 16);
            float hif = __builtin_bit_cast(float, u & 0xffff0000u);
            float lof = f - hif;
            al[j] = (short)(__builtin_bit_cast(unsigned, lof) >> 16);
        }

        const ushort* b = bsm[cur];
#pragma unroll
        for (int g = 0; g < 8; g++) {
            int c = g * 16 + lrow;
            int sw = c & 7;
            short8 bh = *reinterpret_cast<const short8*>(&b[c * 64 + ((kgrp ^ sw) * 8)]);
            short8 bl = *reinterpret_cast<const short8*>(&b[c * 64 + (((4 | kgrp) ^ sw) * 8)]);
            acc[g] = __builtin_amdgcn_mfma_f32_16x16x32_bf16(ah, bh, acc[g], 0, 0, 0);
            acc[g] = __builtin_amdgcn_mfma_f32_16x16x32_bf16(al, bh, acc[g], 0, 0, 0);
            acc[g] = __builtin_amdgcn_mfma_f32_16x16x32_bf16(ah, bl, acc[g], 0, 0, 0);
        }
        __syncthreads();    // readers done + next-slice staging complete
        xa = na; xb = nb;
    }

    // C: row = row0 + kgrp*4 + r, col = g*16 + lrow (verified m89 mapping)
#pragma unroll
    for (int r = 0; r < 4; r++) {
        int row = row0 + kgrp * 4 + r;
        if (row < nrows) {
            float dn = dinv[row];
            float* hrow = H + (size_t)row * 128 + lrow;
            ushort* hbrow = hb16 + (size_t)row * 128 + lrow;
#pragma unroll
            for (int g = 0; g < 8; g++) {
                float v = acc[g][r];
                hrow[g * 16] = v;
                unsigned u = __builtin_bit_cast(unsigned, v * dn);
                hbrow[g * 16] = (ushort)((u + 0x7fffu + ((u >> 16) & 1u)) >> 16);
            }
        }
    }
}

// ------ fused aggregate: out[d] = dinv[d]*(h[d]*dinv[d] + sum hb[src]) -------
// then bias + BN(eval) + ReLU.  One 64-lane wave per node, 4 B/lane gathers.
__global__ __launch_bounds__(256) void agg_k(const float* __restrict__ H,
                                             const uint* __restrict__ hb,
                                             const int* __restrict__ rowptr,
                                             const int* __restrict__ esrc,
                                             const float* __restrict__ dinv,
                                             const float* __restrict__ bias,
                                             const float* __restrict__ gamma,
                                             const float* __restrict__ beta,
                                             const float* __restrict__ rm,
                                             const float* __restrict__ rv,
                                             float* __restrict__ OUT,
                                             int nnodes) {
    int node = blockIdx.x * 4 + (threadIdx.x >> 6);
    if (node >= nnodes) return;
    node = __builtin_amdgcn_readfirstlane(node);
    const int l = threadIdx.x & 63;
    const int c = l * 2;
    const float dn = dinv[node];
    const int beg = rowptr[node], end = rowptr[node + 1];

    float2 hv = *reinterpret_cast<const float2*>(H + (size_t)node * 128 + c);
    float ax0 = hv.x * dn, ay0 = hv.y * dn;
    float ax1 = 0.f, ay1 = 0.f, ax2 = 0.f, ay2 = 0.f, ax3 = 0.f, ay3 = 0.f;
    const uint* hbl = hb + l;

    int j = beg;
    for (; j + 3 < end; j += 4) {
        int s0 = esrc[j], s1 = esrc[j + 1], s2 = esrc[j + 2], s3 = esrc[j + 3];
        uint u0 = hbl[(size_t)s0 * 64];
        uint u1 = hbl[(size_t)s1 * 64];
        uint u2 = hbl[(size_t)s2 * 64];
        uint u3 = hbl[(size_t)s3 * 64];
        ax0 += __builtin_bit_cast(float, u0 << 16);
        ay0 += __builtin_bit_cast(float, u0 & 0xffff0000u);
        ax1 += __builtin_bit_cast(float, u1 << 16);
        ay1 += __builtin_bit_cast(float, u1 & 0xffff0000u);
        ax2 += __builtin_bit_cast(float, u2 << 16);
        ay2 += __builtin_bit_cast(float, u2 & 0xffff0000u);
        ax3 += __builtin_bit_cast(float, u3 << 16);
        ay3 += __builtin_bit_cast(float, u3 & 0xffff0000u);
    }
    for (; j < end; j++) {
        uint u0 = hbl[(size_t)esrc[j] * 64];
        ax0 += __builtin_bit_cast(float, u0 << 16);
        ay0 += __builtin_bit_cast(float, u0 & 0xffff0000u);
    }
    float accx = (ax0 + ax1) + (ax2 + ax3);
    float accy = (ay0 + ay1) + (ay2 + ay3);

    float v0 = accx * dn + bias[c];
    float v1 = accy * dn + bias[c + 1];
    v0 = (v0 - rm[c])     * rsqrtf(rv[c] + EPSV)     * gamma[c]     + beta[c];
    v1 = (v1 - rm[c + 1]) * rsqrtf(rv[c + 1] + EPSV) * gamma[c + 1] + beta[c + 1];
    v0 = fmaxf(v0, 0.0f);
    v1 = fmaxf(v1, 0.0f);

    *reinterpret_cast<float2*>(OUT + (size_t)node * 128 + c) = make_float2(v0, v1);
}

// ---------------- mean pool, stage 1: per-(graph, chunk) partial sums --------
__global__ __launch_bounds__(256) void pool1_k(const float* __restrict__ V,
                                               const int* __restrict__ gstart,
                                               float* __restrict__ partial) {
    __shared__ float sh[256];
    const int g = blockIdx.x >> 5;
    const int p = blockIdx.x & 31;
    const int tx = threadIdx.x;
    const int ch = tx & 127;
    const int sub = tx >> 7;
    const int beg = gstart[g], end = gstart[g + 1];
    const int chunk = (end - beg + 31) >> 5;
    const int s = beg + p * chunk;
    const int e = min(s + chunk, end);
    float acc = 0.0f;
    for (int i = s + sub; i < e; i += 2)
        acc += V[(size_t)i * 128 + ch];
    sh[tx] = acc;
    __syncthreads();
    if (tx < 128)
        partial[(size_t)blockIdx.x * 128 + tx] = sh[tx] + sh[tx + 128];
}

// ---------------- mean pool, stage 2 -----------------------------------------
__global__ __launch_bounds__(128) void pool2_k(const float* __restrict__ partial,
                                               const int* __restrict__ gstart,
                                               float* __restrict__ pooled) {
    const int g = blockIdx.x;
    const int ch = threadIdx.x;
    float s = 0.0f;
#pragma unroll
    for (int p = 0; p < 32; p++)
        s += partial[(size_t)((g << 5) + p) * 128 + ch];
    float cnt = fmaxf((float)(gstart[g + 1] - gstart[g]), 1.0f);
    pooled[g * 128 + ch] = s / cnt;
}

// ---------------- final: out[g][o] = pooled[g] @ Wl + bl ---------------------
__global__ __launch_bounds__(128) void final_k(const float* __restrict__ pooled,
                                               const float* __restrict__ Wl,
                                               const float* __restrict__ bl,
                                               float* __restrict__ out) {
    int tx = threadIdx.x;
    int g = tx >> 1, o = tx & 1;
    float s = 0.0f;
#pragma unroll 8
    for (int c = 0; c < 128; c++) s += pooled[g * 128 + c] * Wl[c * 2 + o];
    out[tx] = s + bl[o];
}

extern "C" void kernel_launch(void* const* d_in, const int* in_sizes, int n_in,
                              void* d_out, int out_size, void* d_ws, size_t ws_size,
                              hipStream_t stream) {
    const float* x      = (const float*)d_in[0];
    const int*   ei     = (const int*)d_in[1];
    const int*   batch  = (const int*)d_in[2];
    const float* W1     = (const float*)d_in[3];
    const float* b1     = (const float*)d_in[4];
    const float* gamma1 = (const float*)d_in[5];
    const float* beta1  = (const float*)d_in[6];
    const float* rm1    = (const float*)d_in[7];
    const float* rv1    = (const float*)d_in[8];
    const float* W2     = (const float*)d_in[9];
    const float* b2     = (const float*)d_in[10];
    const float* gamma2 = (const float*)d_in[11];
    const float* beta2  = (const float*)d_in[12];
    const float* rm2    = (const float*)d_in[13];
    const float* rv2    = (const float*)d_in[14];
    const float* Wl     = (const float*)d_in[15];
    const float* bl     = (const float*)d_in[16];
    float* out = (float*)d_out;

    const int nnodes  = in_sizes[2];
    const int nedges  = in_sizes[1] / 2;
    const int ngraphs = 64;
    const int* srcp = ei;
    const int* dstp = ei + nedges;

    float* wsA     = (float*)d_ws;                       // [nnodes*128]
    float* wsB     = wsA + (size_t)nnodes * 128;         // [nnodes*128]
    float* dinv    = wsB + (size_t)nnodes * 128;         // [nnodes]
    float* pooled  = dinv + nnodes;                      // [64*128]
    float* partial = pooled + 64 * 128;                  // [64*32*128]
    int*   cnt     = (int*)(partial + 64 * 32 * 128);    // [nnodes]
    int*   rowptr  = cnt + nnodes;                       // [nnodes+1]
    int*   cur     = rowptr + nnodes + 1;                // [nnodes]
    int*   bsum    = cur + nnodes;                       // [64]
    int*   gstart  = bsum + 64;                          // [65]
    int*   esrc    = gstart + 65;                        // [nedges]
    uintptr_t wp   = ((uintptr_t)(esrc + nedges) + 15) & ~(uintptr_t)15;
    ushort* wt1hi = (ushort*)wp;                         // [128*512]
    ushort* wt1lo = wt1hi + 512 * 128;
    ushort* wt2hi = wt1lo + 512 * 128;                   // [128*128]
    ushort* wt2lo = wt2hi + 128 * 128;
    ushort* hb16  = (ushort*)(wt2lo + 128 * 128);        // [nnodes*128] bf16
    uint*   hb    = (uint*)hb16;                         // same buffer, uint view

    dim3 blk(256);
    const int gNodes = (nnodes + 255) / 256;
    const int gEdges = (nedges + 255) / 256;
    const int gGemm  = (nnodes + 63) / 64;
    const int gAgg   = (nnodes + 3) / 4;
    const int nScanB = (nnodes + 1023) / 1024;

    // ---- graph preprocessing (CSR by dst + graph segments + W split) ----
    init_k<<<gNodes, blk, 0, stream>>>(cnt, nnodes);
    gstart_k<<<1, 128, 0, stream>>>(batch, gstart, nnodes, ngraphs);
    wprep_k<512><<<(512 * 128) / 256, blk, 0, stream>>>(W1, wt1hi, wt1lo);
    wprep_k<128><<<(128 * 128) / 256, blk, 0, stream>>>(W2, wt2hi, wt2lo);
    degcount_k<<<gEdges, blk, 0, stream>>>(dstp, cnt, nedges);
    dinv_k<<<gNodes, blk, 0, stream>>>(cnt, dinv, nnodes);
    scan1_k<<<nScanB, blk, 0, stream>>>(cnt, rowptr, bsum, nnodes);
    scan2_k<<<1, 64, 0, stream>>>(bsum, nScanB);
    scan3_k<<<nScanB, blk, 0, stream>>>(rowptr, cur, bsum, nnodes, nedges);
    fill_k<<<gEdges, blk, 0, stream>>>(srcp, dstp, cur, esrc, nedges);

    // ---- layer 1: MFMA GEMM (+hb) + fused aggregate/BN/ReLU ----
    gemm_mfma_k<512><<<gGemm, blk, 0, stream>>>(x, wt1hi, wt1lo, dinv, wsA, hb16, nnodes);
    agg_k<<<gAgg, blk, 0, stream>>>(wsA, hb, rowptr, esrc, dinv, b1, gamma1, beta1,
                                    rm1, rv1, wsB, nnodes);

    // ---- layer 2: MFMA GEMM (+hb) + fused aggregate/BN/ReLU ----
    gemm_mfma_k<128><<<gGemm, blk, 0, stream>>>(wsB, wt2hi, wt2lo, dinv, wsA, hb16, nnodes);
    agg_k<<<gAgg, blk, 0, stream>>>(wsA, hb, rowptr, esrc, dinv, b2, gamma2, beta2,
                                    rm2, rv2, wsB, nnodes);

    // ---- readout ----
    pool1_k<<<ngraphs * 32, blk, 0, stream>>>(wsB, gstart, partial);
    pool2_k<<<ngraphs, 128, 0, stream>>>(partial, gstart, pooled);
    final_k<<<1, 128, 0, stream>>>(pooled, Wl, bl, out);
}

// Round 9
// 276.145 us; speedup vs baseline: 1.9592x; 1.0150x over previous
//
#include <hip/hip_runtime.h>

#define EPSV 1e-5f

typedef __attribute__((ext_vector_type(8))) short short8;
typedef __attribute__((ext_vector_type(4))) float f32x4;
typedef unsigned int uint;
typedef unsigned short ushort;

// ---------------- init: cnt=0 ----------------
__global__ __launch_bounds__(256) void init_k(int* __restrict__ cnt, int nnodes) {
    int i = blockIdx.x * 256 + threadIdx.x;
    if (i < nnodes) cnt[i] = 0;
}

// ---------------- graph segment starts via binary search on sorted batch ----
__global__ __launch_bounds__(128) void gstart_k(const int* __restrict__ batch,
                                                int* __restrict__ gstart,
                                                int nnodes, int ngraphs) {
    int g = threadIdx.x;
    if (g > ngraphs) return;
    int lo = 0, hi = nnodes;
    while (lo < hi) {
        int mid = (lo + hi) >> 1;
        if (batch[mid] < g) lo = mid + 1; else hi = mid;
    }
    gstart[g] = lo;
}

__global__ __launch_bounds__(256) void degcount_k(const int* __restrict__ dst,
                                                  int* __restrict__ cnt,
                                                  int nedges) {
    int i = blockIdx.x * 256 + threadIdx.x;
    if (i < nedges) atomicAdd(&cnt[dst[i]], 1);
}

__global__ __launch_bounds__(256) void dinv_k(const int* __restrict__ cnt,
                                              float* __restrict__ dinv, int nnodes) {
    int i = blockIdx.x * 256 + threadIdx.x;
    if (i < nnodes) dinv[i] = rsqrtf(1.0f + (float)cnt[i]);
}

// ---------------- exclusive scan of cnt[] -> rowptr[] ------------------------
__global__ __launch_bounds__(256) void scan1_k(const int* __restrict__ cnt,
                                               int* __restrict__ rowptr,
                                               int* __restrict__ bsum, int n) {
    __shared__ int sh[256];
    const int tx = threadIdx.x;
    const int base = blockIdx.x * 1024;
    int v[4];
    int s = 0;
#pragma unroll
    for (int j = 0; j < 4; j++) {
        int idx = base + tx * 4 + j;
        v[j] = (idx < n) ? cnt[idx] : 0;
        s += v[j];
    }
    sh[tx] = s;
    __syncthreads();
#pragma unroll
    for (int off = 1; off < 256; off <<= 1) {
        int t = (tx >= off) ? sh[tx - off] : 0;
        __syncthreads();
        sh[tx] += t;
        __syncthreads();
    }
    int run = sh[tx] - s;
#pragma unroll
    for (int j = 0; j < 4; j++) {
        int idx = base + tx * 4 + j;
        if (idx < n) rowptr[idx] = run;
        run += v[j];
    }
    if (tx == 255) bsum[blockIdx.x] = sh[255];
}

__global__ __launch_bounds__(64) void scan2_k(int* __restrict__ bsum, int nb) {
    __shared__ int sh[64];
    const int tx = threadIdx.x;
    int v = (tx < nb) ? bsum[tx] : 0;
    sh[tx] = v;
    __syncthreads();
#pragma unroll
    for (int off = 1; off < 64; off <<= 1) {
        int t = (tx >= off) ? sh[tx - off] : 0;
        __syncthreads();
        sh[tx] += t;
        __syncthreads();
    }
    if (tx < nb) bsum[tx] = sh[tx] - v;
}

__global__ __launch_bounds__(256) void scan3_k(int* __restrict__ rowptr,
                                               int* __restrict__ cur,
                                               const int* __restrict__ bsum,
                                               int n, int nedges) {
    const int tx = threadIdx.x;
    const int base = blockIdx.x * 1024;
    int off = bsum[blockIdx.x];
#pragma unroll
    for (int j = 0; j < 4; j++) {
        int idx = base + tx * 4 + j;
        if (idx < n) {
            int r = rowptr[idx] + off;
            rowptr[idx] = r;
            cur[idx] = r;
        }
    }
    if (blockIdx.x == 0 && tx == 0) rowptr[n] = nedges;
}

__global__ __launch_bounds__(256) void fill_k(const int* __restrict__ src,
                                              const int* __restrict__ dst,
                                              int* __restrict__ cur,
                                              int* __restrict__ esrc, int nedges) {
    int i = blockIdx.x * 256 + threadIdx.x;
    if (i >= nedges) return;
    int pos = atomicAdd(&cur[dst[i]], 1);
    esrc[pos] = src[i];
}

// ---------------- W prep: transpose + bf16 hi/lo split -----------------------
template <int K>
__global__ __launch_bounds__(256) void wprep_k(const float* __restrict__ W,
                                               ushort* __restrict__ wThi,
                                               ushort* __restrict__ wTlo) {
    int i = blockIdx.x * 256 + threadIdx.x;
    if (i >= K * 128) return;
    int k = i >> 7, c = i & 127;
    float x = W[i];
    unsigned u = __builtin_bit_cast(unsigned, x);
    ushort hi = (ushort)(u >> 16);
    float hif = __builtin_bit_cast(float, u & 0xffff0000u);
    float lof = x - hif;
    ushort lo = (ushort)(__builtin_bit_cast(unsigned, lof) >> 16);
    wThi[c * K + k] = hi;
    wTlo[c * K + k] = lo;
}

// ---------------- MFMA GEMM: H = X @ W, + fused hb = bf16(H*dinv) -----------
// Split-bf16: acc += xh*wh + xl*wh + xh*wl (fp32 acc).
// 256 thr = 4 waves; wave owns 16 rows x 128 cols. B in 3-buffer LDS rotation:
//   per iter: [vmcnt(6); s_barrier; compute buf[i%3]; STAGE buf[(i+2)%3]].
// STAGE(i+2) overwrites buf[(i-1)%3], whose readers all passed this iter's
// barrier -> race-free. vmcnt(6) = 2 stages (4 loads) + 1 A-prefetch (2 loads)
// guaranteed issued after S(i) -> S(i) complete without full drain.
template <int K>
__global__ __launch_bounds__(256) void gemm_mfma_k(const float* __restrict__ X,
                                                   const ushort* __restrict__ wThi,
                                                   const ushort* __restrict__ wTlo,
                                                   const float* __restrict__ dinv,
                                                   float* __restrict__ H,
                                                   ushort* __restrict__ hb16,
                                                   int nrows) {
    __shared__ ushort bsm[3][8192];   // 3 x 16 KB

    const int tx = threadIdx.x;
    const int wu = __builtin_amdgcn_readfirstlane(tx >> 6);   // wave id (uniform)
    const int l = tx & 63;
    const int lrow = l & 15;
    const int kgrp = l >> 4;
    const int row0 = blockIdx.x * 64 + wu * 16;

    // staging source pointers (per-lane, pre-swizzled): slot s' = s ^ (c&7)
    const ushort* sp[4];
#pragma unroll
    for (int q = 0; q < 4; q++) {
        int chunk = (wu * 4 + q) * 64 + l;       // 16B-chunk id in slice
        int c = chunk >> 3;
        int sl = (chunk & 7) ^ (c & 7);          // unswizzled slot
        sp[q] = ((sl >> 2) ? wTlo : wThi) + (size_t)c * K + (sl & 3) * 8;
    }

    int arow = row0 + lrow;
    if (arow >= nrows) arow = nrows - 1;         // clamp (store guarded)
    const float* xrow = X + (size_t)arow * K + kgrp * 8;

    f32x4 acc[8];
#pragma unroll
    for (int g = 0; g < 8; g++) acc[g] = (f32x4){0.f, 0.f, 0.f, 0.f};

    auto STAGE = [&](int buf, int k0) {
#pragma unroll
        for (int q = 0; q < 4; q++) {
            const ushort* src = sp[q] + k0;
            ushort* dst = &bsm[buf][(wu * 4 + q) * 512];   // +lane*16B by HW
            __builtin_amdgcn_global_load_lds(
                (const __attribute__((address_space(1))) unsigned int*)(const void*)src,
                (__attribute__((address_space(3))) unsigned int*)(void*)dst,
                16, 0, 0);
        }
    };

    constexpr int NIT = K / 32;

    // prologue: stage slices 0,1; pin order so >=8 VMEM ops follow S(0)
    STAGE(0, 0);
    STAGE(1, 32);
    asm volatile("" ::: "memory");
    f32x4 a0x = *reinterpret_cast<const f32x4*>(xrow);
    f32x4 a0y = *reinterpret_cast<const f32x4*>(xrow + 4);
    f32x4 a1x = *reinterpret_cast<const f32x4*>(xrow + 32);
    f32x4 a1y = *reinterpret_cast<const f32x4*>(xrow + 36);

#pragma unroll
    for (int i = 0; i < NIT; i++) {
        if (i + 1 < NIT) asm volatile("s_waitcnt vmcnt(6)" ::: "memory");
        else             asm volatile("s_waitcnt vmcnt(0)" ::: "memory");
        __builtin_amdgcn_s_barrier();
        __builtin_amdgcn_sched_barrier(0);

        // A prefetch: slice i+2 (2 global loads; compiler tracks the reg dep)
        f32x4 a2x = a1x, a2y = a1y;
        if (i + 2 < NIT) {
            a2x = *reinterpret_cast<const f32x4*>(xrow + (i + 2) * 32);
            a2y = *reinterpret_cast<const f32x4*>(xrow + (i + 2) * 32 + 4);
        }

        // A fragment: slice i -> bf16 hi/lo (truncate; lo catches the rest)
        short8 ah, al;
#pragma unroll
        for (int j = 0; j < 8; j++) {
            float f = (j < 4) ? a0x[j] : a0y[j - 4];
            unsigned u = __builtin_bit_cast(unsigned, f);
            ah[j] = (short)(u >> 16);
            float hif = __builtin_bit_cast(float, u & 0xffff0000u);
            float lof = f - hif;
            al[j] = (short)(__builtin_bit_cast(unsigned, lof) >> 16);
        }

        const ushort* b = bsm[i % 3];
#pragma unroll
        for (int g = 0; g < 8; g++) {
            int c = g * 16 + lrow;
            int sw = c & 7;
            short8 bh = *reinterpret_cast<const short8*>(&b[c * 64 + ((kgrp ^ sw) * 8)]);
            short8 bl = *reinterpret_cast<const short8*>(&b[c * 64 + (((4 | kgrp) ^ sw) * 8)]);
            acc[g] = __builtin_amdgcn_mfma_f32_16x16x32_bf16(ah, bh, acc[g], 0, 0, 0);
            acc[g] = __builtin_amdgcn_mfma_f32_16x16x32_bf16(al, bh, acc[g], 0, 0, 0);
            acc[g] = __builtin_amdgcn_mfma_f32_16x16x32_bf16(ah, bl, acc[g], 0, 0, 0);
        }

        // stage slice i+2 into buf[(i+2)%3] == buf[(i-1)%3]: its readers
        // (compute of slice i-1) all passed this iteration's barrier.
        asm volatile("" ::: "memory");
        if (i + 2 < NIT) STAGE((i + 2) % 3, (i + 2) * 32);
        asm volatile("" ::: "memory");

        a0x = a1x; a0y = a1y;
        a1x = a2x; a1y = a2y;
    }

    // C: row = row0 + kgrp*4 + r, col = g*16 + lrow (verified m89 mapping)
#pragma unroll
    for (int r = 0; r < 4; r++) {
        int row = row0 + kgrp * 4 + r;
        if (row < nrows) {
            float dn = dinv[row];
            float* hrow = H + (size_t)row * 128 + lrow;
            ushort* hbrow = hb16 + (size_t)row * 128 + lrow;
#pragma unroll
            for (int g = 0; g < 8; g++) {
                float v = acc[g][r];
                hrow[g * 16] = v;
                unsigned u = __builtin_bit_cast(unsigned, v * dn);
                hbrow[g * 16] = (ushort)((u + 0x7fffu + ((u >> 16) & 1u)) >> 16);
            }
        }
    }
}

// ------ fused aggregate: out[d] = dinv[d]*(h[d]*dinv[d] + sum hb[src]) -------
// then bias + BN(eval) + ReLU.  One 64-lane wave per node, 4 B/lane gathers.
__global__ __launch_bounds__(256) void agg_k(const float* __restrict__ H,
                                             const uint* __restrict__ hb,
                                             const int* __restrict__ rowptr,
                                             const int* __restrict__ esrc,
                                             const float* __restrict__ dinv,
                                             const float* __restrict__ bias,
                                             const float* __restrict__ gamma,
                                             const float* __restrict__ beta,
                                             const float* __restrict__ rm,
                                             const float* __restrict__ rv,
                                             float* __restrict__ OUT,
                                             int nnodes) {
    int node = blockIdx.x * 4 + (threadIdx.x >> 6);
    if (node >= nnodes) return;
    node = __builtin_amdgcn_readfirstlane(node);
    const int l = threadIdx.x & 63;
    const int c = l * 2;
    const float dn = dinv[node];
    const int beg = rowptr[node], end = rowptr[node + 1];

    float2 hv = *reinterpret_cast<const float2*>(H + (size_t)node * 128 + c);
    float ax0 = hv.x * dn, ay0 = hv.y * dn;
    float ax1 = 0.f, ay1 = 0.f, ax2 = 0.f, ay2 = 0.f, ax3 = 0.f, ay3 = 0.f;
    const uint* hbl = hb + l;

    int j = beg;
    for (; j + 3 < end; j += 4) {
        int s0 = esrc[j], s1 = esrc[j + 1], s2 = esrc[j + 2], s3 = esrc[j + 3];
        uint u0 = hbl[(size_t)s0 * 64];
        uint u1 = hbl[(size_t)s1 * 64];
        uint u2 = hbl[(size_t)s2 * 64];
        uint u3 = hbl[(size_t)s3 * 64];
        ax0 += __builtin_bit_cast(float, u0 << 16);
        ay0 += __builtin_bit_cast(float, u0 & 0xffff0000u);
        ax1 += __builtin_bit_cast(float, u1 << 16);
        ay1 += __builtin_bit_cast(float, u1 & 0xffff0000u);
        ax2 += __builtin_bit_cast(float, u2 << 16);
        ay2 += __builtin_bit_cast(float, u2 & 0xffff0000u);
        ax3 += __builtin_bit_cast(float, u3 << 16);
        ay3 += __builtin_bit_cast(float, u3 & 0xffff0000u);
    }
    for (; j < end; j++) {
        uint u0 = hbl[(size_t)esrc[j] * 64];
        ax0 += __builtin_bit_cast(float, u0 << 16);
        ay0 += __builtin_bit_cast(float, u0 & 0xffff0000u);
    }
    float accx = (ax0 + ax1) + (ax2 + ax3);
    float accy = (ay0 + ay1) + (ay2 + ay3);

    float v0 = accx * dn + bias[c];
    float v1 = accy * dn + bias[c + 1];
    v0 = (v0 - rm[c])     * rsqrtf(rv[c] + EPSV)     * gamma[c]     + beta[c];
    v1 = (v1 - rm[c + 1]) * rsqrtf(rv[c + 1] + EPSV) * gamma[c + 1] + beta[c + 1];
    v0 = fmaxf(v0, 0.0f);
    v1 = fmaxf(v1, 0.0f);

    *reinterpret_cast<float2*>(OUT + (size_t)node * 128 + c) = make_float2(v0, v1);
}

// ---------------- mean pool, stage 1: per-(graph, chunk) partial sums --------
__global__ __launch_bounds__(256) void pool1_k(const float* __restrict__ V,
                                               const int* __restrict__ gstart,
                                               float* __restrict__ partial) {
    __shared__ float sh[256];
    const int g = blockIdx.x >> 5;
    const int p = blockIdx.x & 31;
    const int tx = threadIdx.x;
    const int ch = tx & 127;
    const int sub = tx >> 7;
    const int beg = gstart[g], end = gstart[g + 1];
    const int chunk = (end - beg + 31) >> 5;
    const int s = beg + p * chunk;
    const int e = min(s + chunk, end);
    float acc = 0.0f;
    for (int i = s + sub; i < e; i += 2)
        acc += V[(size_t)i * 128 + ch];
    sh[tx] = acc;
    __syncthreads();
    if (tx < 128)
        partial[(size_t)blockIdx.x * 128 + tx] = sh[tx] + sh[tx + 128];
}

// ---------------- mean pool, stage 2 -----------------------------------------
__global__ __launch_bounds__(128) void pool2_k(const float* __restrict__ partial,
                                               const int* __restrict__ gstart,
                                               float* __restrict__ pooled) {
    const int g = blockIdx.x;
    const int ch = threadIdx.x;
    float s = 0.0f;
#pragma unroll
    for (int p = 0; p < 32; p++)
        s += partial[(size_t)((g << 5) + p) * 128 + ch];
    float cnt = fmaxf((float)(gstart[g + 1] - gstart[g]), 1.0f);
    pooled[g * 128 + ch] = s / cnt;
}

// ---------------- final: out[g][o] = pooled[g] @ Wl + bl ---------------------
__global__ __launch_bounds__(128) void final_k(const float* __restrict__ pooled,
                                               const float* __restrict__ Wl,
                                               const float* __restrict__ bl,
                                               float* __restrict__ out) {
    int tx = threadIdx.x;
    int g = tx >> 1, o = tx & 1;
    float s = 0.0f;
#pragma unroll 8
    for (int c = 0; c < 128; c++) s += pooled[g * 128 + c] * Wl[c * 2 + o];
    out[tx] = s + bl[o];
}

extern "C" void kernel_launch(void* const* d_in, const int* in_sizes, int n_in,
                              void* d_out, int out_size, void* d_ws, size_t ws_size,
                              hipStream_t stream) {
    const float* x      = (const float*)d_in[0];
    const int*   ei     = (const int*)d_in[1];
    const int*   batch  = (const int*)d_in[2];
    const float* W1     = (const float*)d_in[3];
    const float* b1     = (const float*)d_in[4];
    const float* gamma1 = (const float*)d_in[5];
    const float* beta1  = (const float*)d_in[6];
    const float* rm1    = (const float*)d_in[7];
    const float* rv1    = (const float*)d_in[8];
    const float* W2     = (const float*)d_in[9];
    const float* b2     = (const float*)d_in[10];
    const float* gamma2 = (const float*)d_in[11];
    const float* beta2  = (const float*)d_in[12];
    const float* rm2    = (const float*)d_in[13];
    const float* rv2    = (const float*)d_in[14];
    const float* Wl     = (const float*)d_in[15];
    const float* bl     = (const float*)d_in[16];
    float* out = (float*)d_out;

    const int nnodes  = in_sizes[2];
    const int nedges  = in_sizes[1] / 2;
    const int ngraphs = 64;
    const int* srcp = ei;
    const int* dstp = ei + nedges;

    float* wsA     = (float*)d_ws;                       // [nnodes*128]
    float* wsB     = wsA + (size_t)nnodes * 128;         // [nnodes*128]
    float* dinv    = wsB + (size_t)nnodes * 128;         // [nnodes]
    float* pooled  = dinv + nnodes;                      // [64*128]
    float* partial = pooled + 64 * 128;                  // [64*32*128]
    int*   cnt     = (int*)(partial + 64 * 32 * 128);    // [nnodes]
    int*   rowptr  = cnt + nnodes;                       // [nnodes+1]
    int*   cur     = rowptr + nnodes + 1;                // [nnodes]
    int*   bsum    = cur + nnodes;                       // [64]
    int*   gstart  = bsum + 64;                          // [65]
    int*   esrc    = gstart + 65;                        // [nedges]
    uintptr_t wp   = ((uintptr_t)(esrc + nedges) + 15) & ~(uintptr_t)15;
    ushort* wt1hi = (ushort*)wp;                         // [128*512]
    ushort* wt1lo = wt1hi + 512 * 128;
    ushort* wt2hi = wt1lo + 512 * 128;                   // [128*128]
    ushort* wt2lo = wt2hi + 128 * 128;
    ushort* hb16  = (ushort*)(wt2lo + 128 * 128);        // [nnodes*128] bf16
    uint*   hb    = (uint*)hb16;                         // same buffer, uint view

    dim3 blk(256);
    const int gNodes = (nnodes + 255) / 256;
    const int gEdges = (nedges + 255) / 256;
    const int gGemm  = (nnodes + 63) / 64;
    const int gAgg   = (nnodes + 3) / 4;
    const int nScanB = (nnodes + 1023) / 1024;

    // ---- graph preprocessing (CSR by dst + graph segments + W split) ----
    init_k<<<gNodes, blk, 0, stream>>>(cnt, nnodes);
    gstart_k<<<1, 128, 0, stream>>>(batch, gstart, nnodes, ngraphs);
    wprep_k<512><<<(512 * 128) / 256, blk, 0, stream>>>(W1, wt1hi, wt1lo);
    wprep_k<128><<<(128 * 128) / 256, blk, 0, stream>>>(W2, wt2hi, wt2lo);
    degcount_k<<<gEdges, blk, 0, stream>>>(dstp, cnt, nedges);
    dinv_k<<<gNodes, blk, 0, stream>>>(cnt, dinv, nnodes);
    scan1_k<<<nScanB, blk, 0, stream>>>(cnt, rowptr, bsum, nnodes);
    scan2_k<<<1, 64, 0, stream>>>(bsum, nScanB);
    scan3_k<<<nScanB, blk, 0, stream>>>(rowptr, cur, bsum, nnodes, nedges);
    fill_k<<<gEdges, blk, 0, stream>>>(srcp, dstp, cur, esrc, nedges);

    // ---- layer 1: MFMA GEMM (+hb) + fused aggregate/BN/ReLU ----
    gemm_mfma_k<512><<<gGemm, blk, 0, stream>>>(x, wt1hi, wt1lo, dinv, wsA, hb16, nnodes);
    agg_k<<<gAgg, blk, 0, stream>>>(wsA, hb, rowptr, esrc, dinv, b1, gamma1, beta1,
                                    rm1, rv1, wsB, nnodes);

    // ---- layer 2: MFMA GEMM (+hb) + fused aggregate/BN/ReLU ----
    gemm_mfma_k<128><<<gGemm, blk, 0, stream>>>(wsB, wt2hi, wt2lo, dinv, wsA, hb16, nnodes);
    agg_k<<<gAgg, blk, 0, stream>>>(wsA, hb, rowptr, esrc, dinv, b2, gamma2, beta2,
                                    rm2, rv2, wsB, nnodes);

    // ---- readout ----
    pool1_k<<<ngraphs * 32, blk, 0, stream>>>(wsB, gstart, partial);
    pool2_k<<<ngraphs, 128, 0, stream>>>(partial, gstart, pooled);
    final_k<<<1, 128, 0, stream>>>(pooled, Wl, bl, out);
}

// Round 10
// 258.432 us; speedup vs baseline: 2.0935x; 1.0685x over previous
//
#include <hip/hip_runtime.h>

#define EPSV 1e-5f

typedef __attribute__((ext_vector_type(8))) short short8;
typedef __attribute__((ext_vector_type(4))) float f32x4;
typedef unsigned int uint;
typedef unsigned short ushort;

// ---------------- init: cnt=0 ----------------
__global__ __launch_bounds__(256) void init_k(int* __restrict__ cnt, int nnodes) {
    int i = blockIdx.x * 256 + threadIdx.x;
    if (i < nnodes) cnt[i] = 0;
}

// ---------------- graph segment starts via binary search on sorted batch ----
__global__ __launch_bounds__(128) void gstart_k(const int* __restrict__ batch,
                                                int* __restrict__ gstart,
                                                int nnodes, int ngraphs) {
    int g = threadIdx.x;
    if (g > ngraphs) return;
    int lo = 0, hi = nnodes;
    while (lo < hi) {
        int mid = (lo + hi) >> 1;
        if (batch[mid] < g) lo = mid + 1; else hi = mid;
    }
    gstart[g] = lo;
}

__global__ __launch_bounds__(256) void degcount_k(const int* __restrict__ dst,
                                                  int* __restrict__ cnt,
                                                  int nedges) {
    int i = blockIdx.x * 256 + threadIdx.x;
    if (i < nedges) atomicAdd(&cnt[dst[i]], 1);
}

__global__ __launch_bounds__(256) void dinv_k(const int* __restrict__ cnt,
                                              float* __restrict__ dinv, int nnodes) {
    int i = blockIdx.x * 256 + threadIdx.x;
    if (i < nnodes) dinv[i] = rsqrtf(1.0f + (float)cnt[i]);
}

// ---------------- exclusive scan of cnt[] -> rowptr[] ------------------------
__global__ __launch_bounds__(256) void scan1_k(const int* __restrict__ cnt,
                                               int* __restrict__ rowptr,
                                               int* __restrict__ bsum, int n) {
    __shared__ int sh[256];
    const int tx = threadIdx.x;
    const int base = blockIdx.x * 1024;
    int v[4];
    int s = 0;
#pragma unroll
    for (int j = 0; j < 4; j++) {
        int idx = base + tx * 4 + j;
        v[j] = (idx < n) ? cnt[idx] : 0;
        s += v[j];
    }
    sh[tx] = s;
    __syncthreads();
#pragma unroll
    for (int off = 1; off < 256; off <<= 1) {
        int t = (tx >= off) ? sh[tx - off] : 0;
        __syncthreads();
        sh[tx] += t;
        __syncthreads();
    }
    int run = sh[tx] - s;
#pragma unroll
    for (int j = 0; j < 4; j++) {
        int idx = base + tx * 4 + j;
        if (idx < n) rowptr[idx] = run;
        run += v[j];
    }
    if (tx == 255) bsum[blockIdx.x] = sh[255];
}

__global__ __launch_bounds__(64) void scan2_k(int* __restrict__ bsum, int nb) {
    __shared__ int sh[64];
    const int tx = threadIdx.x;
    int v = (tx < nb) ? bsum[tx] : 0;
    sh[tx] = v;
    __syncthreads();
#pragma unroll
    for (int off = 1; off < 64; off <<= 1) {
        int t = (tx >= off) ? sh[tx - off] : 0;
        __syncthreads();
        sh[tx] += t;
        __syncthreads();
    }
    if (tx < nb) bsum[tx] = sh[tx] - v;
}

__global__ __launch_bounds__(256) void scan3_k(int* __restrict__ rowptr,
                                               int* __restrict__ cur,
                                               const int* __restrict__ bsum,
                                               int n, int nedges) {
    const int tx = threadIdx.x;
    const int base = blockIdx.x * 1024;
    int off = bsum[blockIdx.x];
#pragma unroll
    for (int j = 0; j < 4; j++) {
        int idx = base + tx * 4 + j;
        if (idx < n) {
            int r = rowptr[idx] + off;
            rowptr[idx] = r;
            cur[idx] = r;
        }
    }
    if (blockIdx.x == 0 && tx == 0) rowptr[n] = nedges;
}

__global__ __launch_bounds__(256) void fill_k(const int* __restrict__ src,
                                              const int* __restrict__ dst,
                                              int* __restrict__ cur,
                                              int* __restrict__ esrc, int nedges) {
    int i = blockIdx.x * 256 + threadIdx.x;
    if (i >= nedges) return;
    int pos = atomicAdd(&cur[dst[i]], 1);
    esrc[pos] = src[i];
}

// ---------------- W prep: transpose + bf16 RNE -------------------------------
// wT[c][k] (ushort bf16 bits), c in [0,128), k in [0,K)
template <int K>
__global__ __launch_bounds__(256) void wprep_k(const float* __restrict__ W,
                                               ushort* __restrict__ wT) {
    int i = blockIdx.x * 256 + threadIdx.x;
    if (i >= K * 128) return;
    int k = i >> 7, c = i & 127;
    unsigned u = __builtin_bit_cast(unsigned, W[i]);
    wT[c * K + k] = (ushort)((u + 0x7fffu + ((u >> 16) & 1u)) >> 16);
}

// ---------------- MFMA GEMM: H = X @ W, + fused hb = bf16(H*dinv) -----------
// A split-bf16 (ah+al, exact), B pure bf16-RNE: acc += ah*wb + al*wb.
// 256 thr = 4 waves; wave owns 16 rows x 128 cols. B in 3-buffer LDS rotation,
// each buffer = one 64-k slice pair (16 KB): [c 128][slot 8 x 16B],
// slot s = sub*4 + kgrp (k-offset s*8), stored at s' = s ^ (c&7).
// Per iter: [vmcnt(8); s_barrier; prefetch A(i+1); compute buf[i%3];
//            STAGE buf[(i+2)%3]].  vmcnt(8) = S(i+1)[4]+A(i)[4] newest allowed
// -> forces STAGE(i) complete without full drain.
template <int K>
__global__ __launch_bounds__(256) void gemm_mfma_k(const float* __restrict__ X,
                                                   const ushort* __restrict__ wT,
                                                   const float* __restrict__ dinv,
                                                   float* __restrict__ H,
                                                   ushort* __restrict__ hb16,
                                                   int nrows) {
    __shared__ ushort bsm[3][8192];   // 3 x 16 KB

    const int tx = threadIdx.x;
    const int wu = __builtin_amdgcn_readfirstlane(tx >> 6);   // wave id (uniform)
    const int l = tx & 63;
    const int lrow = l & 15;
    const int kgrp = l >> 4;
    const int row0 = blockIdx.x * 64 + wu * 16;

    // staging source pointers (per-lane, pre-swizzled): phys slot = s ^ (c&7)
    const ushort* sp[4];
#pragma unroll
    for (int q = 0; q < 4; q++) {
        int chunk = (wu * 4 + q) * 64 + l;       // 16B-chunk id in slice pair
        int c = chunk >> 3;
        int s = (chunk & 7) ^ (c & 7);           // unswizzled slot -> k-off s*8
        sp[q] = wT + (size_t)c * K + s * 8;
    }

    int arow = row0 + lrow;
    if (arow >= nrows) arow = nrows - 1;         // clamp (store guarded)
    const float* xrow = X + (size_t)arow * K + kgrp * 8;

    f32x4 acc[8];
#pragma unroll
    for (int g = 0; g < 8; g++) acc[g] = (f32x4){0.f, 0.f, 0.f, 0.f};

    auto STAGE = [&](int buf, int k0) {
#pragma unroll
        for (int q = 0; q < 4; q++) {
            const ushort* src = sp[q] + k0;
            ushort* dst = &bsm[buf][(wu * 4 + q) * 512];   // +lane*16B by HW
            __builtin_amdgcn_global_load_lds(
                (const __attribute__((address_space(1))) unsigned int*)(const void*)src,
                (__attribute__((address_space(3))) unsigned int*)(void*)dst,
                16, 0, 0);
        }
    };

    constexpr int NIT = K / 64;

    // prologue: stage slice pairs 0,1; then A for iter 0
    STAGE(0, 0);
    STAGE(1, 64);
    asm volatile("" ::: "memory");
    f32x4 c0 = *reinterpret_cast<const f32x4*>(xrow);
    f32x4 c1 = *reinterpret_cast<const f32x4*>(xrow + 4);
    f32x4 c2 = *reinterpret_cast<const f32x4*>(xrow + 32);
    f32x4 c3 = *reinterpret_cast<const f32x4*>(xrow + 36);

#pragma unroll
    for (int i = 0; i < NIT; i++) {
        if (i + 1 < NIT) asm volatile("s_waitcnt vmcnt(8)" ::: "memory");
        else             asm volatile("s_waitcnt vmcnt(0)" ::: "memory");
        __builtin_amdgcn_s_barrier();
        __builtin_amdgcn_sched_barrier(0);

        // A prefetch: iter i+1 (4 global loads; compiler tracks the reg dep)
        f32x4 n0 = c0, n1 = c1, n2 = c2, n3 = c3;
        if (i + 1 < NIT) {
            const float* nx = xrow + (i + 1) * 64;
            n0 = *reinterpret_cast<const f32x4*>(nx);
            n1 = *reinterpret_cast<const f32x4*>(nx + 4);
            n2 = *reinterpret_cast<const f32x4*>(nx + 32);
            n3 = *reinterpret_cast<const f32x4*>(nx + 36);
        }

        const ushort* b = bsm[i % 3];
#pragma unroll
        for (int sub = 0; sub < 2; sub++) {
            // A fragment: 8 contiguous f32 -> bf16 hi/lo (exact split)
            short8 ah, al;
#pragma unroll
            for (int j = 0; j < 8; j++) {
                float f = (sub == 0) ? ((j < 4) ? c0[j] : c1[j - 4])
                                     : ((j < 4) ? c2[j] : c3[j - 4]);
                unsigned u = __builtin_bit_cast(unsigned, f);
                ah[j] = (short)(u >> 16);
                float hif = __builtin_bit_cast(float, u & 0xffff0000u);
                float lof = f - hif;
                al[j] = (short)(__builtin_bit_cast(unsigned, lof) >> 16);
            }
#pragma unroll
            for (int g = 0; g < 8; g++) {
                int c = g * 16 + lrow;
                int phys = (sub * 4 + kgrp) ^ (c & 7);
                short8 bb = *reinterpret_cast<const short8*>(&b[c * 64 + phys * 8]);
                acc[g] = __builtin_amdgcn_mfma_f32_16x16x32_bf16(ah, bb, acc[g], 0, 0, 0);
                acc[g] = __builtin_amdgcn_mfma_f32_16x16x32_bf16(al, bb, acc[g], 0, 0, 0);
            }
        }

        // stage slice pair i+2 into buf[(i+2)%3] == buf[(i-1)%3]: its readers
        // (compute of i-1) all passed this iteration's barrier.
        asm volatile("" ::: "memory");
        if (i + 2 < NIT) STAGE((i + 2) % 3, (i + 2) * 64);
        asm volatile("" ::: "memory");

        c0 = n0; c1 = n1; c2 = n2; c3 = n3;
    }

    // C: row = row0 + kgrp*4 + r, col = g*16 + lrow (verified m89 mapping)
#pragma unroll
    for (int r = 0; r < 4; r++) {
        int row = row0 + kgrp * 4 + r;
        if (row < nrows) {
            float dn = dinv[row];
            float* hrow = H + (size_t)row * 128 + lrow;
            ushort* hbrow = hb16 + (size_t)row * 128 + lrow;
#pragma unroll
            for (int g = 0; g < 8; g++) {
                float v = acc[g][r];
                hrow[g * 16] = v;
                unsigned u = __builtin_bit_cast(unsigned, v * dn);
                hbrow[g * 16] = (ushort)((u + 0x7fffu + ((u >> 16) & 1u)) >> 16);
            }
        }
    }
}

// ------ fused aggregate: out[d] = dinv[d]*(h[d]*dinv[d] + sum hb[src]) -------
// then bias + BN(eval) + ReLU.  One 64-lane wave per node, 4 B/lane gathers.
__global__ __launch_bounds__(256) void agg_k(const float* __restrict__ H,
                                             const uint* __restrict__ hb,
                                             const int* __restrict__ rowptr,
                                             const int* __restrict__ esrc,
                                             const float* __restrict__ dinv,
                                             const float* __restrict__ bias,
                                             const float* __restrict__ gamma,
                                             const float* __restrict__ beta,
                                             const float* __restrict__ rm,
                                             const float* __restrict__ rv,
                                             float* __restrict__ OUT,
                                             int nnodes) {
    int node = blockIdx.x * 4 + (threadIdx.x >> 6);
    if (node >= nnodes) return;
    node = __builtin_amdgcn_readfirstlane(node);
    const int l = threadIdx.x & 63;
    const int c = l * 2;
    const float dn = dinv[node];
    const int beg = rowptr[node], end = rowptr[node + 1];

    float2 hv = *reinterpret_cast<const float2*>(H + (size_t)node * 128 + c);
    float ax0 = hv.x * dn, ay0 = hv.y * dn;
    float ax1 = 0.f, ay1 = 0.f, ax2 = 0.f, ay2 = 0.f, ax3 = 0.f, ay3 = 0.f;
    const uint* hbl = hb + l;

    int j = beg;
    for (; j + 3 < end; j += 4) {
        int s0 = esrc[j], s1 = esrc[j + 1], s2 = esrc[j + 2], s3 = esrc[j + 3];
        uint u0 = hbl[(size_t)s0 * 64];
        uint u1 = hbl[(size_t)s1 * 64];
        uint u2 = hbl[(size_t)s2 * 64];
        uint u3 = hbl[(size_t)s3 * 64];
        ax0 += __builtin_bit_cast(float, u0 << 16);
        ay0 += __builtin_bit_cast(float, u0 & 0xffff0000u);
        ax1 += __builtin_bit_cast(float, u1 << 16);
        ay1 += __builtin_bit_cast(float, u1 & 0xffff0000u);
        ax2 += __builtin_bit_cast(float, u2 << 16);
        ay2 += __builtin_bit_cast(float, u2 & 0xffff0000u);
        ax3 += __builtin_bit_cast(float, u3 << 16);
        ay3 += __builtin_bit_cast(float, u3 & 0xffff0000u);
    }
    for (; j < end; j++) {
        uint u0 = hbl[(size_t)esrc[j] * 64];
        ax0 += __builtin_bit_cast(float, u0 << 16);
        ay0 += __builtin_bit_cast(float, u0 & 0xffff0000u);
    }
    float accx = (ax0 + ax1) + (ax2 + ax3);
    float accy = (ay0 + ay1) + (ay2 + ay3);

    float v0 = accx * dn + bias[c];
    float v1 = accy * dn + bias[c + 1];
    v0 = (v0 - rm[c])     * rsqrtf(rv[c] + EPSV)     * gamma[c]     + beta[c];
    v1 = (v1 - rm[c + 1]) * rsqrtf(rv[c + 1] + EPSV) * gamma[c + 1] + beta[c + 1];
    v0 = fmaxf(v0, 0.0f);
    v1 = fmaxf(v1, 0.0f);

    *reinterpret_cast<float2*>(OUT + (size_t)node * 128 + c) = make_float2(v0, v1);
}

// ---------------- mean pool, stage 1: per-(graph, chunk) partial sums --------
__global__ __launch_bounds__(256) void pool1_k(const float* __restrict__ V,
                                               const int* __restrict__ gstart,
                                               float* __restrict__ partial) {
    __shared__ float sh[256];
    const int g = blockIdx.x >> 5;
    const int p = blockIdx.x & 31;
    const int tx = threadIdx.x;
    const int ch = tx & 127;
    const int sub = tx >> 7;
    const int beg = gstart[g], end = gstart[g + 1];
    const int chunk = (end - beg + 31) >> 5;
    const int s = beg + p * chunk;
    const int e = min(s + chunk, end);
    float acc = 0.0f;
    for (int i = s + sub; i < e; i += 2)
        acc += V[(size_t)i * 128 + ch];
    sh[tx] = acc;
    __syncthreads();
    if (tx < 128)
        partial[(size_t)blockIdx.x * 128 + tx] = sh[tx] + sh[tx + 128];
}

// ---------------- mean pool, stage 2 -----------------------------------------
__global__ __launch_bounds__(128) void pool2_k(const float* __restrict__ partial,
                                               const int* __restrict__ gstart,
                                               float* __restrict__ pooled) {
    const int g = blockIdx.x;
    const int ch = threadIdx.x;
    float s = 0.0f;
#pragma unroll
    for (int p = 0; p < 32; p++)
        s += partial[(size_t)((g << 5) + p) * 128 + ch];
    float cnt = fmaxf((float)(gstart[g + 1] - gstart[g]), 1.0f);
    pooled[g * 128 + ch] = s / cnt;
}

// ---------------- final: out[g][o] = pooled[g] @ Wl + bl ---------------------
__global__ __launch_bounds__(128) void final_k(const float* __restrict__ pooled,
                                               const float* __restrict__ Wl,
                                               const float* __restrict__ bl,
                                               float* __restrict__ out) {
    int tx = threadIdx.x;
    int g = tx >> 1, o = tx & 1;
    float s = 0.0f;
#pragma unroll 8
    for (int c = 0; c < 128; c++) s += pooled[g * 128 + c] * Wl[c * 2 + o];
    out[tx] = s + bl[o];
}

extern "C" void kernel_launch(void* const* d_in, const int* in_sizes, int n_in,
                              void* d_out, int out_size, void* d_ws, size_t ws_size,
                              hipStream_t stream) {
    const float* x      = (const float*)d_in[0];
    const int*   ei     = (const int*)d_in[1];
    const int*   batch  = (const int*)d_in[2];
    const float* W1     = (const float*)d_in[3];
    const float* b1     = (const float*)d_in[4];
    const float* gamma1 = (const float*)d_in[5];
    const float* beta1  = (const float*)d_in[6];
    const float* rm1    = (const float*)d_in[7];
    const float* rv1    = (const float*)d_in[8];
    const float* W2     = (const float*)d_in[9];
    const float* b2     = (const float*)d_in[10];
    const float* gamma2 = (const float*)d_in[11];
    const float* beta2  = (const float*)d_in[12];
    const float* rm2    = (const float*)d_in[13];
    const float* rv2    = (const float*)d_in[14];
    const float* Wl     = (const float*)d_in[15];
    const float* bl     = (const float*)d_in[16];
    float* out = (float*)d_out;

    const int nnodes  = in_sizes[2];
    const int nedges  = in_sizes[1] / 2;
    const int ngraphs = 64;
    const int* srcp = ei;
    const int* dstp = ei + nedges;

    float* wsA     = (float*)d_ws;                       // [nnodes*128]
    float* wsB     = wsA + (size_t)nnodes * 128;         // [nnodes*128]
    float* dinv    = wsB + (size_t)nnodes * 128;         // [nnodes]
    float* pooled  = dinv + nnodes;                      // [64*128]
    float* partial = pooled + 64 * 128;                  // [64*32*128]
    int*   cnt     = (int*)(partial + 64 * 32 * 128);    // [nnodes]
    int*   rowptr  = cnt + nnodes;                       // [nnodes+1]
    int*   cur     = rowptr + nnodes + 1;                // [nnodes]
    int*   bsum    = cur + nnodes;                       // [64]
    int*   gstart  = bsum + 64;                          // [65]
    int*   esrc    = gstart + 65;                        // [nedges]
    uintptr_t wp   = ((uintptr_t)(esrc + nedges) + 15) & ~(uintptr_t)15;
    ushort* wt1  = (ushort*)wp;                          // [128*512]
    ushort* wt2  = wt1 + 512 * 128;                      // [128*128]
    ushort* hb16 = wt2 + 128 * 128;                      // [nnodes*128] bf16
    uint*   hb   = (uint*)hb16;                          // same buffer, uint view

    dim3 blk(256);
    const int gNodes = (nnodes + 255) / 256;
    const int gEdges = (nedges + 255) / 256;
    const int gGemm  = (nnodes + 63) / 64;
    const int gAgg   = (nnodes + 3) / 4;
    const int nScanB = (nnodes + 1023) / 1024;

    // ---- graph preprocessing (CSR by dst + graph segments + W prep) ----
    init_k<<<gNodes, blk, 0, stream>>>(cnt, nnodes);
    gstart_k<<<1, 128, 0, stream>>>(batch, gstart, nnodes, ngraphs);
    wprep_k<512><<<(512 * 128) / 256, blk, 0, stream>>>(W1, wt1);
    wprep_k<128><<<(128 * 128) / 256, blk, 0, stream>>>(W2, wt2);
    degcount_k<<<gEdges, blk, 0, stream>>>(dstp, cnt, nedges);
    dinv_k<<<gNodes, blk, 0, stream>>>(cnt, dinv, nnodes);
    scan1_k<<<nScanB, blk, 0, stream>>>(cnt, rowptr, bsum, nnodes);
    scan2_k<<<1, 64, 0, stream>>>(bsum, nScanB);
    scan3_k<<<nScanB, blk, 0, stream>>>(rowptr, cur, bsum, nnodes, nedges);
    fill_k<<<gEdges, blk, 0, stream>>>(srcp, dstp, cur, esrc, nedges);

    // ---- layer 1: MFMA GEMM (+hb) + fused aggregate/BN/ReLU ----
    gemm_mfma_k<512><<<gGemm, blk, 0, stream>>>(x, wt1, dinv, wsA, hb16, nnodes);
    agg_k<<<gAgg, blk, 0, stream>>>(wsA, hb, rowptr, esrc, dinv, b1, gamma1, beta1,
                                    rm1, rv1, wsB, nnodes);

    // ---- layer 2: MFMA GEMM (+hb) + fused aggregate/BN/ReLU ----
    gemm_mfma_k<128><<<gGemm, blk, 0, stream>>>(wsB, wt2, dinv, wsA, hb16, nnodes);
    agg_k<<<gAgg, blk, 0, stream>>>(wsA, hb, rowptr, esrc, dinv, b2, gamma2, beta2,
                                    rm2, rv2, wsB, nnodes);

    // ---- readout ----
    pool1_k<<<ngraphs * 32, blk, 0, stream>>>(wsB, gstart, partial);
    pool2_k<<<ngraphs, 128, 0, stream>>>(partial, gstart, pooled);
    final_k<<<1, 128, 0, stream>>>(pooled, Wl, bl, out);
}